// Round 4
// baseline (1270.804 us; speedup 1.0000x reference)
//
#include <hip/hip_runtime.h>
#include <stdint.h>

typedef short bf16x8 __attribute__((ext_vector_type(8)));
typedef float f32x4 __attribute__((ext_vector_type(4)));

constexpr float cEPS = 1e-5f;
constexpr float cSLOPE = 0.2f;

__device__ __forceinline__ unsigned short f2b(float f){
  unsigned u = __float_as_uint(f);
  u = (u + 0x7fffu + ((u >> 16) & 1u)) >> 16;
  return (unsigned short)u;
}
__device__ __forceinline__ float b2f(unsigned short b){
  return __uint_as_float(((unsigned)b) << 16);
}

// ---------------- preprocessing ----------------
__global__ void k_f32_to_bf16(const float* __restrict__ in, unsigned short* __restrict__ out, int n4){
  int i = blockIdx.x * 256 + threadIdx.x;
  if(i >= n4) return;
  float4 v = ((const float4*)in)[i];
  ushort4 o = { f2b(v.x), f2b(v.y), f2b(v.z), f2b(v.w) };
  ((ushort4*)out)[i] = o;
}

__global__ void k_build_wt(const float* __restrict__ Wl, const float* __restrict__ Wr,
                           const float* __restrict__ skW, const float* __restrict__ pjW,
                           unsigned short* __restrict__ wt){
  int idx = blockIdx.x * 256 + threadIdx.x;
  if(idx >= 19 * 16384) return;
  int mat = idx >> 14, r = idx & 16383;
  int n = r >> 7, k = r & 127;
  const float* src;
  if(mat < 8)       src = Wl + mat * 16384;
  else if(mat < 16) src = Wr + (mat - 8) * 16384;
  else if(mat < 18) src = skW + (mat - 16) * 16384;
  else              src = pjW;
  wt[idx] = f2b(src[k * 128 + n]);
}

// ---------------- counting sort by dst ----------------
__global__ void k_zero_u32(unsigned int* __restrict__ p, int n){
  int i = blockIdx.x * 256 + threadIdx.x;
  if(i < n) p[i] = 0u;
}
__global__ void k_hist_dst(const int* __restrict__ dst, unsigned int* __restrict__ cnt, int E){
  int i = blockIdx.x * 256 + threadIdx.x;
  if(i < E) atomicAdd(cnt + dst[i], 1u);
}
__global__ void k_scan(const unsigned int* __restrict__ cnt, unsigned int* __restrict__ off, int nt){
  __shared__ unsigned int sums[256];
  __shared__ unsigned int total;
  int chunk = (nt + 255) / 256;
  int b0 = threadIdx.x * chunk;
  int b1 = min(b0 + chunk, nt);
  unsigned int s = 0;
  for(int i = b0; i < b1; ++i) s += cnt[i];
  sums[threadIdx.x] = s;
  __syncthreads();
  if(threadIdx.x == 0){
    unsigned int acc = 0;
    for(int t = 0; t < 256; ++t){ unsigned int v = sums[t]; sums[t] = acc; acc += v; }
    total = acc;
  }
  __syncthreads();
  unsigned int acc = sums[threadIdx.x];
  for(int i = b0; i < b1; ++i){ off[i] = acc; acc += cnt[i]; }
  if(threadIdx.x == 0) off[nt] = total;
}
__global__ void k_scatter_dst(const int* __restrict__ dst, unsigned int* __restrict__ cursor,
                              int* __restrict__ perm, int E){
  int i = blockIdx.x * 256 + threadIdx.x;
  if(i < E){
    unsigned int pos = atomicAdd(cursor + dst[i], 1u);
    perm[pos] = i;
  }
}

// ---------------- GEMM ----------------
template<bool OUT_BF16>
__global__ __launch_bounds__(256) void k_gemm(
    const unsigned short* __restrict__ A, int M,
    const unsigned short* __restrict__ wtBase, long wtStride,
    const float* __restrict__ biasBase, int biasStride,
    void* __restrict__ outBase, long outStride)
{
  const unsigned short* Wt = wtBase + (long)blockIdx.y * wtStride;
  const float* bias = biasBase + (long)blockIdx.y * biasStride;
  const int wave = threadIdx.x >> 6, lane = threadIdx.x & 63;
  const int l16 = lane & 15, lhi = lane >> 4;

  bf16x8 bfr[8][4];
  #pragma unroll
  for(int cb = 0; cb < 8; ++cb)
    #pragma unroll
    for(int kb = 0; kb < 4; ++kb)
      bfr[cb][kb] = *(const bf16x8*)(Wt + (cb*16 + l16)*128 + kb*32 + lhi*8);

  const int row0 = blockIdx.x * 64 + wave * 16;
  const int arow = row0 + l16;
  const bf16x8 zf = {0,0,0,0,0,0,0,0};
  bf16x8 afr[4];
  if(arow < M){
    #pragma unroll
    for(int kb = 0; kb < 4; ++kb)
      afr[kb] = *(const bf16x8*)(A + (long)arow*128 + kb*32 + lhi*8);
  } else {
    #pragma unroll
    for(int kb = 0; kb < 4; ++kb) afr[kb] = zf;
  }

  const f32x4 z4 = {0.f,0.f,0.f,0.f};
  f32x4 acc[8];
  #pragma unroll
  for(int cb = 0; cb < 8; ++cb) acc[cb] = z4;
  #pragma unroll
  for(int cb = 0; cb < 8; ++cb)
    #pragma unroll
    for(int kb = 0; kb < 4; ++kb)
      acc[cb] = __builtin_amdgcn_mfma_f32_16x16x32_bf16(afr[kb], bfr[cb][kb], acc[cb], 0, 0, 0);

  #pragma unroll
  for(int cb = 0; cb < 8; ++cb){
    int col = cb*16 + l16;
    float bv = bias[col];
    #pragma unroll
    for(int q = 0; q < 4; ++q){
      int rrow = row0 + lhi*4 + q;
      if(rrow < M){
        float v = acc[cb][q] + bv;
        long oidx = (long)blockIdx.y * outStride + (long)rrow * 128 + col;
        if(OUT_BF16) ((unsigned short*)outBase)[oidx] = f2b(v);
        else         ((float*)outBase)[oidx] = v;
      }
    }
  }
}

// ---------------- per-dst fused attention+aggregate+BN ----------------
__global__ __launch_bounds__(64) void k_dst_agg(
    const unsigned int* __restrict__ off, const int* __restrict__ perm,
    const int* __restrict__ src, const int* __restrict__ ea,
    const unsigned short* __restrict__ xl, const unsigned short* __restrict__ xr,
    const float* __restrict__ att,
    const float* __restrict__ conv_b, const float* __restrict__ bn_g, const float* __restrict__ bn_b,
    const float* __restrict__ bn_m, const float* __restrict__ bn_v,
    float* __restrict__ out, int N, int nt, int jcount)
{
  const int t = blockIdx.x;
  const int lane = threadIdx.x;
  const int sub  = lane >> 4;
  const int l16  = lane & 15;
  const int h    = l16 >> 2;
  const unsigned e0 = off[t], e1 = off[t+1];

  bf16x8 xrv[4];
  float4 attv[4][2];
  for(int r = 0; r < jcount; ++r){
    xrv[r] = *(const bf16x8*)(xr + ((long)r*nt + t)*128 + l16*8);
    attv[r][0] = ((const float4*)(att + r*128 + l16*8))[0];
    attv[r][1] = ((const float4*)(att + r*128 + l16*8))[1];
  }

  float mx[4];
  #pragma unroll
  for(int r = 0; r < 4; ++r) mx[r] = -3.0e38f;

  for(unsigned e = e0 + sub; e < e1; e += 4){
    int eid = perm[e];
    int r = ea[eid];
    int s = src[eid];
    bf16x8 xlv = *(const bf16x8*)(xl + ((long)r*N + s)*128 + l16*8);
    float part = 0.f;
    #pragma unroll
    for(int q = 0; q < 8; ++q){
      float m = b2f((unsigned short)xlv[q]) + b2f((unsigned short)xrv[r][q]);
      m = m >= 0.f ? m : cSLOPE * m;
      float atv = (q<4) ? ((q==0)?attv[r][0].x:(q==1)?attv[r][0].y:(q==2)?attv[r][0].z:attv[r][0].w)
                        : ((q==4)?attv[r][1].x:(q==5)?attv[r][1].y:(q==6)?attv[r][1].z:attv[r][1].w);
      part += m * atv;
    }
    part += __shfl_xor(part, 1);
    part += __shfl_xor(part, 2);
    mx[r] = fmaxf(mx[r], part);
  }
  #pragma unroll
  for(int r = 0; r < 4; ++r){
    mx[r] = fmaxf(mx[r], __shfl_xor(mx[r], 16));
    mx[r] = fmaxf(mx[r], __shfl_xor(mx[r], 32));
  }

  float den[4] = {0.f, 0.f, 0.f, 0.f};
  float accv[4][8];
  #pragma unroll
  for(int r = 0; r < 4; ++r)
    #pragma unroll
    for(int q = 0; q < 8; ++q) accv[r][q] = 0.f;

  for(unsigned e = e0 + sub; e < e1; e += 4){
    int eid = perm[e];
    int r = ea[eid];
    int s = src[eid];
    bf16x8 xlv = *(const bf16x8*)(xl + ((long)r*N + s)*128 + l16*8);
    float part = 0.f;
    #pragma unroll
    for(int q = 0; q < 8; ++q){
      float m = b2f((unsigned short)xlv[q]) + b2f((unsigned short)xrv[r][q]);
      m = m >= 0.f ? m : cSLOPE * m;
      float atv = (q<4) ? ((q==0)?attv[r][0].x:(q==1)?attv[r][0].y:(q==2)?attv[r][0].z:attv[r][0].w)
                        : ((q==4)?attv[r][1].x:(q==5)?attv[r][1].y:(q==6)?attv[r][1].z:attv[r][1].w);
      part += m * atv;
    }
    part += __shfl_xor(part, 1);
    part += __shfl_xor(part, 2);
    float p = __expf(part - mx[r]);
    if((l16 & 3) == 0) den[r] += p;
    #pragma unroll
    for(int q = 0; q < 8; ++q) accv[r][q] += p * b2f((unsigned short)xlv[q]);
  }

  #pragma unroll
  for(int r = 0; r < 4; ++r){
    den[r] += __shfl_xor(den[r], 16);
    den[r] += __shfl_xor(den[r], 32);
    #pragma unroll
    for(int q = 0; q < 8; ++q){
      accv[r][q] += __shfl_xor(accv[r][q], 16);
      accv[r][q] += __shfl_xor(accv[r][q], 32);
    }
  }

  float4 o0 = ((const float4*)(out + (long)t*128 + l16*8))[0];
  float4 o1 = ((const float4*)(out + (long)t*128 + l16*8))[1];
  float oc[8] = {o0.x,o0.y,o0.z,o0.w,o1.x,o1.y,o1.z,o1.w};
  for(int r = 0; r < jcount; ++r){
    float dh = __shfl(den[r], h << 2);   // head sum lives in lane l16 = h*4 (sub 0 == all subs)
    float inv = 1.f / fmaxf(dh, 1e-16f);
    #pragma unroll
    for(int q = 0; q < 8; ++q){
      int c = l16*8 + q;
      float cb = conv_b[r*128 + c], gg = bn_g[r*128 + c], bb = bn_b[r*128 + c];
      float mm = bn_m[r*128 + c],  vv = bn_v[r*128 + c];
      oc[q] += (accv[r][q] * inv + cb - mm) * rsqrtf(vv + cEPS) * gg + bb;
    }
  }
  float4 w0 = {oc[0],oc[1],oc[2],oc[3]}, w1 = {oc[4],oc[5],oc[6],oc[7]};
  if(sub == 0){
    ((float4*)(out + (long)t*128 + l16*8))[0] = w0;
    ((float4*)(out + (long)t*128 + l16*8))[1] = w1;
  }
}

// ---------------- ELU ----------------
__global__ void k_elu_act(const float* __restrict__ in, unsigned short* __restrict__ outBf,
                          float* __restrict__ outF32, int n4){
  int i = blockIdx.x * 256 + threadIdx.x;
  if(i >= n4) return;
  float4 v = ((const float4*)in)[i];
  float4 e;
  e.x = v.x > 0.f ? v.x : __expf(v.x) - 1.f;
  e.y = v.y > 0.f ? v.y : __expf(v.y) - 1.f;
  e.z = v.z > 0.f ? v.z : __expf(v.z) - 1.f;
  e.w = v.w > 0.f ? v.w : __expf(v.w) - 1.f;
  ushort4 o = { f2b(e.x), f2b(e.y), f2b(e.z), f2b(e.w) };
  ((ushort4*)outBf)[i] = o;
  if(outF32) ((float4*)outF32)[i] = e;
}

// ---------------- projection BN + PReLU ----------------
__global__ void k_pbn_prelu(float* __restrict__ hbuf, const float* __restrict__ g, const float* __restrict__ b,
                            const float* __restrict__ m, const float* __restrict__ v,
                            const float* __restrict__ a, int n4){
  int i = blockIdx.x * 256 + threadIdx.x;
  if(i >= n4) return;
  int c4 = i & 31;
  float4 x  = ((const float4*)hbuf)[i];
  float4 gg = ((const float4*)g)[c4], bb = ((const float4*)b)[c4];
  float4 mm = ((const float4*)m)[c4], vv = ((const float4*)v)[c4];
  float al = a[0];
  float4 y;
  y.x = (x.x - mm.x) * rsqrtf(vv.x + cEPS) * gg.x + bb.x; y.x = y.x > 0.f ? y.x : al * y.x;
  y.y = (x.y - mm.y) * rsqrtf(vv.y + cEPS) * gg.y + bb.y; y.y = y.y > 0.f ? y.y : al * y.y;
  y.z = (x.z - mm.z) * rsqrtf(vv.z + cEPS) * gg.z + bb.z; y.z = y.z > 0.f ? y.z : al * y.z;
  y.w = (x.w - mm.w) * rsqrtf(vv.w + cEPS) * gg.w + bb.w; y.w = y.w > 0.f ? y.w : al * y.w;
  ((float4*)hbuf)[i] = y;
}

extern "C" void kernel_launch(void* const* d_in, const int* in_sizes, int n_in,
                              void* d_out, int out_size, void* d_ws, size_t ws_size,
                              hipStream_t stream)
{
  const float* x0     = (const float*)d_in[0];
  const int*   src0   = (const int*)d_in[1];
  const int*   dst0   = (const int*)d_in[2];
  const int*   ea0    = (const int*)d_in[3];
  const int*   src1   = (const int*)d_in[4];
  const int*   dst1   = (const int*)d_in[5];
  const int*   ea1    = (const int*)d_in[6];
  const float* Wl     = (const float*)d_in[7];
  const float* Wr     = (const float*)d_in[8];
  const float* bl     = (const float*)d_in[9];
  const float* br     = (const float*)d_in[10];
  const float* att    = (const float*)d_in[11];
  const float* conv_b = (const float*)d_in[12];
  const float* bn_g   = (const float*)d_in[13];
  const float* bn_b   = (const float*)d_in[14];
  const float* bn_m   = (const float*)d_in[15];
  const float* bn_v   = (const float*)d_in[16];
  const float* skip_W = (const float*)d_in[17];
  const float* skip_b = (const float*)d_in[18];
  const float* proj_W = (const float*)d_in[19];
  const float* proj_b = (const float*)d_in[20];
  const float* pbn_g  = (const float*)d_in[21];
  const float* pbn_b  = (const float*)d_in[22];
  const float* pbn_m  = (const float*)d_in[23];
  const float* pbn_v  = (const float*)d_in[24];
  const float* prelu_a= (const float*)d_in[25];

  const int N0 = in_sizes[0] / 128;
  const int E0 = in_sizes[1];
  const int E1 = in_sizes[4];
  const int N1 = 30000;
  const int N2 = 8000;
  const int jc = 4;

  auto al = [](size_t x){ return (x + 255) & ~(size_t)255; };
  char* p = (char*)d_ws;
  auto carve = [&](size_t bytes){ char* r = p; p += al(bytes); return r; };
  unsigned short* wt    = (unsigned short*)carve((size_t)19*16384*2);
  unsigned short* xbf   = (unsigned short*)carve((size_t)N0*256);
  unsigned short* xlb   = (unsigned short*)carve((size_t)jc*N0*256);
  unsigned short* xrb   = (unsigned short*)carve((size_t)jc*N1*256);
  unsigned int*   cnt   = (unsigned int*)carve((size_t)(N1+1)*4);
  unsigned int*   off   = (unsigned int*)carve((size_t)(N1+1)*4);
  unsigned int*   cur   = (unsigned int*)carve((size_t)(N1+1)*4);
  int*            perm  = (int*)carve((size_t)E0*4);
  float*          out1  = (float*)carve((size_t)N1*512);

  k_f32_to_bf16<<<(N0*32 + 255)/256, 256, 0, stream>>>(x0, xbf, N0*32);
  k_build_wt<<<(19*16384 + 255)/256, 256, 0, stream>>>(Wl, Wr, skip_W, proj_W, wt);

  auto run_layer = [&](int li, int N, int nt, const int* src, const int* dst, const int* ea, int E){
    k_zero_u32<<<(nt + 256)/256, 256, 0, stream>>>(cnt, nt + 1);
    k_hist_dst<<<(E + 255)/256, 256, 0, stream>>>(dst, cnt, E);
    k_scan<<<1, 256, 0, stream>>>(cnt, off, nt);
    hipMemcpyAsync(cur, off, (size_t)nt*4, hipMemcpyDeviceToDevice, stream);
    k_scatter_dst<<<(E + 255)/256, 256, 0, stream>>>(dst, cur, perm, E);

    k_gemm<false><<<dim3((nt+63)/64, 1), 256, 0, stream>>>(
        xbf, nt, wt + (16+li)*16384, 0, skip_b + li*128, 0, out1, 0);
    k_gemm<true><<<dim3((N+63)/64, jc), 256, 0, stream>>>(
        xbf, N,  wt + (li*4)*16384,   16384, bl + (li*4)*128, 128, xlb, (long)N*128);
    k_gemm<true><<<dim3((nt+63)/64, jc), 256, 0, stream>>>(
        xbf, nt, wt + (8+li*4)*16384, 16384, br + (li*4)*128, 128, xrb, (long)nt*128);
    k_dst_agg<<<nt, 64, 0, stream>>>(
        off, perm, src, ea, xlb, xrb, att + li*512,
        conv_b + li*512, bn_g + li*512, bn_b + li*512, bn_m + li*512, bn_v + li*512,
        out1, N, nt, jc);
  };

  run_layer(0, N0, N1, src0, dst0, ea0, E0);
  k_elu_act<<<(N1*32 + 255)/256, 256, 0, stream>>>(out1, xbf, nullptr, N1*32);
  run_layer(1, N1, N2, src1, dst1, ea1, E1);

  float* outX = (float*)d_out;
  float* outP = (float*)d_out + (size_t)N2*128;
  k_elu_act<<<(N2*32 + 255)/256, 256, 0, stream>>>(out1, xbf, outX, N2*32);
  k_gemm<false><<<dim3((N2+63)/64, 1), 256, 0, stream>>>(
      xbf, N2, wt + 18*16384, 0, proj_b, 0, outP, 0);
  k_pbn_prelu<<<(N2*32 + 255)/256, 256, 0, stream>>>(outP, pbn_g, pbn_b, pbn_m, pbn_v, prelu_a, N2*32);
}

// Round 6
// 890.831 us; speedup vs baseline: 1.4265x; 1.4265x over previous
//
#include <hip/hip_runtime.h>
#include <stdint.h>

typedef short bf16x8 __attribute__((ext_vector_type(8)));
typedef float f32x4 __attribute__((ext_vector_type(4)));

constexpr float cEPS = 1e-5f;
constexpr float cSLOPE = 0.2f;

__device__ __forceinline__ unsigned short f2b(float f){
  unsigned u = __float_as_uint(f);
  u = (u + 0x7fffu + ((u >> 16) & 1u)) >> 16;
  return (unsigned short)u;
}
__device__ __forceinline__ float b2f(unsigned short b){
  return __uint_as_float(((unsigned)b) << 16);
}

// ---------------- preprocessing ----------------
__global__ void k_f32_to_bf16(const float* __restrict__ in, unsigned short* __restrict__ out, int n4){
  int i = blockIdx.x * 256 + threadIdx.x;
  if(i >= n4) return;
  float4 v = ((const float4*)in)[i];
  ushort4 o = { f2b(v.x), f2b(v.y), f2b(v.z), f2b(v.w) };
  ((ushort4*)out)[i] = o;
}

__global__ void k_build_wt(const float* __restrict__ Wl, const float* __restrict__ Wr,
                           const float* __restrict__ skW, const float* __restrict__ pjW,
                           unsigned short* __restrict__ wt){
  int idx = blockIdx.x * 256 + threadIdx.x;
  if(idx >= 19 * 16384) return;
  int mat = idx >> 14, r = idx & 16383;
  int n = r >> 7, k = r & 127;
  const float* src;
  if(mat < 8)       src = Wl + mat * 16384;
  else if(mat < 16) src = Wr + (mat - 8) * 16384;
  else if(mat < 18) src = skW + (mat - 16) * 16384;
  else              src = pjW;
  wt[idx] = f2b(src[k * 128 + n]);
}

// ---------------- counting sort by key = dst*4 + ea ----------------
__global__ void k_zero_u32(unsigned int* __restrict__ p, int n){
  int i = blockIdx.x * 256 + threadIdx.x;
  if(i < n) p[i] = 0u;
}
__global__ void k_hist_key(const int* __restrict__ dst, const int* __restrict__ ea,
                           unsigned int* __restrict__ cnt, int E){
  int i = blockIdx.x * 256 + threadIdx.x;
  if(i < E) atomicAdd(cnt + (dst[i]*4 + ea[i]), 1u);
}
__global__ void k_scan(const unsigned int* __restrict__ cnt, unsigned int* __restrict__ off, int nbins){
  __shared__ unsigned int sums[256];
  __shared__ unsigned int total;
  int chunk = (nbins + 255) / 256;
  int b0 = threadIdx.x * chunk;
  int b1 = min(b0 + chunk, nbins);
  unsigned int s = 0;
  for(int i = b0; i < b1; ++i) s += cnt[i];
  sums[threadIdx.x] = s;
  __syncthreads();
  if(threadIdx.x == 0){
    unsigned int acc = 0;
    for(int t = 0; t < 256; ++t){ unsigned int v = sums[t]; sums[t] = acc; acc += v; }
    total = acc;
  }
  __syncthreads();
  unsigned int acc = sums[threadIdx.x];
  for(int i = b0; i < b1; ++i){ off[i] = acc; acc += cnt[i]; }
  if(threadIdx.x == 0) off[nbins] = total;
}
__global__ void k_scatter_key(const int* __restrict__ dst, const int* __restrict__ ea,
                              const int* __restrict__ src,
                              unsigned int* __restrict__ cursor,
                              int* __restrict__ psrc, int E){
  int i = blockIdx.x * 256 + threadIdx.x;
  if(i < E){
    unsigned int pos = atomicAdd(cursor + (dst[i]*4 + ea[i]), 1u);
    psrc[pos] = src[i];   // store src directly: removes one indirection in agg
  }
}

// ---------------- GEMM ----------------
template<bool OUT_BF16>
__global__ __launch_bounds__(256) void k_gemm(
    const unsigned short* __restrict__ A, int M,
    const unsigned short* __restrict__ wtBase, long wtStride,
    const float* __restrict__ biasBase, int biasStride,
    void* __restrict__ outBase, long outStride)
{
  const unsigned short* Wt = wtBase + (long)blockIdx.y * wtStride;
  const float* bias = biasBase + (long)blockIdx.y * biasStride;
  const int wave = threadIdx.x >> 6, lane = threadIdx.x & 63;
  const int l16 = lane & 15, lhi = lane >> 4;

  bf16x8 bfr[8][4];
  #pragma unroll
  for(int cb = 0; cb < 8; ++cb)
    #pragma unroll
    for(int kb = 0; kb < 4; ++kb)
      bfr[cb][kb] = *(const bf16x8*)(Wt + (cb*16 + l16)*128 + kb*32 + lhi*8);

  const int row0 = blockIdx.x * 64 + wave * 16;
  const int arow = row0 + l16;
  const bf16x8 zf = {0,0,0,0,0,0,0,0};
  bf16x8 afr[4];
  if(arow < M){
    #pragma unroll
    for(int kb = 0; kb < 4; ++kb)
      afr[kb] = *(const bf16x8*)(A + (long)arow*128 + kb*32 + lhi*8);
  } else {
    #pragma unroll
    for(int kb = 0; kb < 4; ++kb) afr[kb] = zf;
  }

  const f32x4 z4 = {0.f,0.f,0.f,0.f};
  f32x4 acc[8];
  #pragma unroll
  for(int cb = 0; cb < 8; ++cb) acc[cb] = z4;
  #pragma unroll
  for(int cb = 0; cb < 8; ++cb)
    #pragma unroll
    for(int kb = 0; kb < 4; ++kb)
      acc[cb] = __builtin_amdgcn_mfma_f32_16x16x32_bf16(afr[kb], bfr[cb][kb], acc[cb], 0, 0, 0);

  #pragma unroll
  for(int cb = 0; cb < 8; ++cb){
    int col = cb*16 + l16;
    float bv = bias[col];
    #pragma unroll
    for(int q = 0; q < 4; ++q){
      int rrow = row0 + lhi*4 + q;
      if(rrow < M){
        float v = acc[cb][q] + bv;
        long oidx = (long)blockIdx.y * outStride + (long)rrow * 128 + col;
        if(OUT_BF16) ((unsigned short*)outBase)[oidx] = f2b(v);
        else         ((float*)outBase)[oidx] = v;
      }
    }
  }
}

// ---------------- per-dst fused attention+aggregate+BN (uniform r, online softmax) ----------------
// One wave per dst t. Edges sorted by key dst*4+r: segment (t,r) = [off[t*4+r], off[t*4+r+1]).
// Lane layout: sub = lane>>4 (edge slot), l16 = lane&15 (channel group: c = l16*8..l16*8+7,
// all inside head h = l16>>2). psrc[] holds pre-permuted src ids.
__global__ __launch_bounds__(64) void k_dst_agg(
    const unsigned int* __restrict__ off, const int* __restrict__ psrc,
    const unsigned short* __restrict__ xl, const unsigned short* __restrict__ xr,
    const float* __restrict__ att,
    const float* __restrict__ conv_b, const float* __restrict__ bn_g, const float* __restrict__ bn_b,
    const float* __restrict__ bn_m, const float* __restrict__ bn_v,
    float* __restrict__ out, int N, int nt)
{
  const int t = blockIdx.x;
  const int lane = threadIdx.x;
  const int sub  = lane >> 4;
  const int l16  = lane & 15;

  float4 o0 = ((const float4*)(out + (long)t*128 + l16*8))[0];
  float4 o1 = ((const float4*)(out + (long)t*128 + l16*8))[1];
  float oc[8] = {o0.x,o0.y,o0.z,o0.w,o1.x,o1.y,o1.z,o1.w};

  for(int r = 0; r < 4; ++r){                      // r is WAVE-UNIFORM -> all reg indices static
    const bf16x8 xrv = *(const bf16x8*)(xr + ((long)r*nt + t)*128 + l16*8);
    const float4 a0 = ((const float4*)(att + r*128 + l16*8))[0];
    const float4 a1 = ((const float4*)(att + r*128 + l16*8))[1];
    const float av[8] = {a0.x,a0.y,a0.z,a0.w,a1.x,a1.y,a1.z,a1.w};
    float xrf[8];
    #pragma unroll
    for(int q = 0; q < 8; ++q) xrf[q] = b2f((unsigned short)xrv[q]);

    const unsigned s0 = off[t*4 + r], s1 = off[t*4 + r + 1];

    float m = -3.0e38f, den = 0.f;
    float acc[8];
    #pragma unroll
    for(int q = 0; q < 8; ++q) acc[q] = 0.f;

    for(unsigned e = s0 + sub; e < s1; e += 4){
      int s = psrc[e];
      bf16x8 xlv = *(const bf16x8*)(xl + ((long)r*N + s)*128 + l16*8);
      float xlf[8];
      #pragma unroll
      for(int q = 0; q < 8; ++q) xlf[q] = b2f((unsigned short)xlv[q]);
      float part = 0.f;
      #pragma unroll
      for(int q = 0; q < 8; ++q){
        float v = xlf[q] + xrf[q];
        v = v >= 0.f ? v : cSLOPE * v;
        part += v * av[q];
      }
      part += __shfl_xor(part, 1);
      part += __shfl_xor(part, 2);      // all 4 lanes of the quad now hold head logit
      // online softmax update (per-lane state; replicated within quad)
      float nm = fmaxf(m, part);
      float corr = __expf(m - nm);      // ==1 when m unchanged; ==0 from -3e38 start
      float p = __expf(part - nm);
      den = den * corr + p;
      #pragma unroll
      for(int q = 0; q < 8; ++q) acc[q] = acc[q] * corr + p * xlf[q];
      m = nm;
    }

    // merge the 4 edge-slots (lanes differing in bits 4,5)
    #pragma unroll
    for(int ofs = 16; ofs <= 32; ofs <<= 1){
      float m2 = __shfl_xor(m, ofs);
      float d2 = __shfl_xor(den, ofs);
      float M = fmaxf(m, m2);
      float sA = __expf(m - M), sB = __expf(m2 - M);
      den = den * sA + d2 * sB;
      #pragma unroll
      for(int q = 0; q < 8; ++q){
        float a2 = __shfl_xor(acc[q], ofs);
        acc[q] = acc[q] * sA + a2 * sB;
      }
      m = M;
    }

    const float inv = 1.f / fmaxf(den, 1e-16f);
    const float4 cb0 = ((const float4*)(conv_b + r*128 + l16*8))[0];
    const float4 cb1 = ((const float4*)(conv_b + r*128 + l16*8))[1];
    const float4 gg0 = ((const float4*)(bn_g  + r*128 + l16*8))[0];
    const float4 gg1 = ((const float4*)(bn_g  + r*128 + l16*8))[1];
    const float4 bb0 = ((const float4*)(bn_b  + r*128 + l16*8))[0];
    const float4 bb1 = ((const float4*)(bn_b  + r*128 + l16*8))[1];
    const float4 mm0 = ((const float4*)(bn_m  + r*128 + l16*8))[0];
    const float4 mm1 = ((const float4*)(bn_m  + r*128 + l16*8))[1];
    const float4 vv0 = ((const float4*)(bn_v  + r*128 + l16*8))[0];
    const float4 vv1 = ((const float4*)(bn_v  + r*128 + l16*8))[1];
    const float cbv[8] = {cb0.x,cb0.y,cb0.z,cb0.w,cb1.x,cb1.y,cb1.z,cb1.w};
    const float ggv[8] = {gg0.x,gg0.y,gg0.z,gg0.w,gg1.x,gg1.y,gg1.z,gg1.w};
    const float bbv[8] = {bb0.x,bb0.y,bb0.z,bb0.w,bb1.x,bb1.y,bb1.z,bb1.w};
    const float mmv[8] = {mm0.x,mm0.y,mm0.z,mm0.w,mm1.x,mm1.y,mm1.z,mm1.w};
    const float vvv[8] = {vv0.x,vv0.y,vv0.z,vv0.w,vv1.x,vv1.y,vv1.z,vv1.w};
    #pragma unroll
    for(int q = 0; q < 8; ++q)
      oc[q] += (acc[q] * inv + cbv[q] - mmv[q]) * rsqrtf(vvv[q] + cEPS) * ggv[q] + bbv[q];
  }

  if(sub == 0){
    float4 w0 = {oc[0],oc[1],oc[2],oc[3]}, w1 = {oc[4],oc[5],oc[6],oc[7]};
    ((float4*)(out + (long)t*128 + l16*8))[0] = w0;
    ((float4*)(out + (long)t*128 + l16*8))[1] = w1;
  }
}

// ---------------- ELU ----------------
__global__ void k_elu_act(const float* __restrict__ in, unsigned short* __restrict__ outBf,
                          float* __restrict__ outF32, int n4){
  int i = blockIdx.x * 256 + threadIdx.x;
  if(i >= n4) return;
  float4 v = ((const float4*)in)[i];
  float4 e;
  e.x = v.x > 0.f ? v.x : __expf(v.x) - 1.f;
  e.y = v.y > 0.f ? v.y : __expf(v.y) - 1.f;
  e.z = v.z > 0.f ? v.z : __expf(v.z) - 1.f;
  e.w = v.w > 0.f ? v.w : __expf(v.w) - 1.f;
  ushort4 o = { f2b(e.x), f2b(e.y), f2b(e.z), f2b(e.w) };
  ((ushort4*)outBf)[i] = o;
  if(outF32) ((float4*)outF32)[i] = e;
}

// ---------------- projection BN + PReLU ----------------
__global__ void k_pbn_prelu(float* __restrict__ hbuf, const float* __restrict__ g, const float* __restrict__ b,
                            const float* __restrict__ m, const float* __restrict__ v,
                            const float* __restrict__ a, int n4){
  int i = blockIdx.x * 256 + threadIdx.x;
  if(i >= n4) return;
  int c4 = i & 31;
  float4 x  = ((const float4*)hbuf)[i];
  float4 gg = ((const float4*)g)[c4], bb = ((const float4*)b)[c4];
  float4 mm = ((const float4*)m)[c4], vv = ((const float4*)v)[c4];
  float al = a[0];
  float4 y;
  y.x = (x.x - mm.x) * rsqrtf(vv.x + cEPS) * gg.x + bb.x; y.x = y.x > 0.f ? y.x : al * y.x;
  y.y = (x.y - mm.y) * rsqrtf(vv.y + cEPS) * gg.y + bb.y; y.y = y.y > 0.f ? y.y : al * y.y;
  y.z = (x.z - mm.z) * rsqrtf(vv.z + cEPS) * gg.z + bb.z; y.z = y.z > 0.f ? y.z : al * y.z;
  y.w = (x.w - mm.w) * rsqrtf(vv.w + cEPS) * gg.w + bb.w; y.w = y.w > 0.f ? y.w : al * y.w;
  ((float4*)hbuf)[i] = y;
}

extern "C" void kernel_launch(void* const* d_in, const int* in_sizes, int n_in,
                              void* d_out, int out_size, void* d_ws, size_t ws_size,
                              hipStream_t stream)
{
  const float* x0     = (const float*)d_in[0];
  const int*   src0   = (const int*)d_in[1];
  const int*   dst0   = (const int*)d_in[2];
  const int*   ea0    = (const int*)d_in[3];
  const int*   src1   = (const int*)d_in[4];
  const int*   dst1   = (const int*)d_in[5];
  const int*   ea1    = (const int*)d_in[6];
  const float* Wl     = (const float*)d_in[7];
  const float* Wr     = (const float*)d_in[8];
  const float* bl     = (const float*)d_in[9];
  const float* br     = (const float*)d_in[10];
  const float* att    = (const float*)d_in[11];
  const float* conv_b = (const float*)d_in[12];
  const float* bn_g   = (const float*)d_in[13];
  const float* bn_b   = (const float*)d_in[14];
  const float* bn_m   = (const float*)d_in[15];
  const float* bn_v   = (const float*)d_in[16];
  const float* skip_W = (const float*)d_in[17];
  const float* skip_b = (const float*)d_in[18];
  const float* proj_W = (const float*)d_in[19];
  const float* proj_b = (const float*)d_in[20];
  const float* pbn_g  = (const float*)d_in[21];
  const float* pbn_b  = (const float*)d_in[22];
  const float* pbn_m  = (const float*)d_in[23];
  const float* pbn_v  = (const float*)d_in[24];
  const float* prelu_a= (const float*)d_in[25];

  const int N0 = in_sizes[0] / 128;
  const int E0 = in_sizes[1];
  const int E1 = in_sizes[4];
  const int N1 = 30000;
  const int N2 = 8000;
  const int jc = 4;

  auto al = [](size_t x){ return (x + 255) & ~(size_t)255; };
  char* p = (char*)d_ws;
  auto carve = [&](size_t bytes){ char* r = p; p += al(bytes); return r; };
  unsigned short* wt    = (unsigned short*)carve((size_t)19*16384*2);
  unsigned short* xbf   = (unsigned short*)carve((size_t)N0*256);
  unsigned short* xlb   = (unsigned short*)carve((size_t)jc*N0*256);
  unsigned short* xrb   = (unsigned short*)carve((size_t)jc*N1*256);
  unsigned int*   cnt   = (unsigned int*)carve((size_t)(N1*4+1)*4);
  unsigned int*   off   = (unsigned int*)carve((size_t)(N1*4+1)*4);
  unsigned int*   cur   = (unsigned int*)carve((size_t)(N1*4+1)*4);
  int*            psrc  = (int*)carve((size_t)E0*4);
  float*          out1  = (float*)carve((size_t)N1*512);

  k_f32_to_bf16<<<(N0*32 + 255)/256, 256, 0, stream>>>(x0, xbf, N0*32);
  k_build_wt<<<(19*16384 + 255)/256, 256, 0, stream>>>(Wl, Wr, skip_W, proj_W, wt);

  auto run_layer = [&](int li, int N, int nt, const int* src, const int* dst, const int* ea, int E){
    const int nbins = nt * 4;
    k_zero_u32<<<(nbins + 256)/256, 256, 0, stream>>>(cnt, nbins + 1);
    k_hist_key<<<(E + 255)/256, 256, 0, stream>>>(dst, ea, cnt, E);
    k_scan<<<1, 256, 0, stream>>>(cnt, off, nbins);
    hipMemcpyAsync(cur, off, (size_t)nbins*4, hipMemcpyDeviceToDevice, stream);
    k_scatter_key<<<(E + 255)/256, 256, 0, stream>>>(dst, ea, src, cur, psrc, E);

    k_gemm<false><<<dim3((nt+63)/64, 1), 256, 0, stream>>>(
        xbf, nt, wt + (16+li)*16384, 0, skip_b + li*128, 0, out1, 0);
    k_gemm<true><<<dim3((N+63)/64, jc), 256, 0, stream>>>(
        xbf, N,  wt + (li*4)*16384,   16384, bl + (li*4)*128, 128, xlb, (long)N*128);
    k_gemm<true><<<dim3((nt+63)/64, jc), 256, 0, stream>>>(
        xbf, nt, wt + (8+li*4)*16384, 16384, br + (li*4)*128, 128, xrb, (long)nt*128);
    k_dst_agg<<<nt, 64, 0, stream>>>(
        off, psrc, xlb, xrb, att + li*512,
        conv_b + li*512, bn_g + li*512, bn_b + li*512, bn_m + li*512, bn_v + li*512,
        out1, N, nt);
  };

  run_layer(0, N0, N1, src0, dst0, ea0, E0);
  k_elu_act<<<(N1*32 + 255)/256, 256, 0, stream>>>(out1, xbf, nullptr, N1*32);
  run_layer(1, N1, N2, src1, dst1, ea1, E1);

  float* outX = (float*)d_out;
  float* outP = (float*)d_out + (size_t)N2*128;
  k_elu_act<<<(N2*32 + 255)/256, 256, 0, stream>>>(out1, xbf, outX, N2*32);
  k_gemm<false><<<dim3((N2+63)/64, 1), 256, 0, stream>>>(
      xbf, N2, wt + 18*16384, 0, proj_b, 0, outP, 0);
  k_pbn_prelu<<<(N2*32 + 255)/256, 256, 0, stream>>>(outP, pbn_g, pbn_b, pbn_m, pbn_v, prelu_a, N2*32);
}

// Round 7
// 664.901 us; speedup vs baseline: 1.9113x; 1.3398x over previous
//
#include <hip/hip_runtime.h>
#include <stdint.h>

typedef short bf16x8 __attribute__((ext_vector_type(8)));
typedef float f32x4 __attribute__((ext_vector_type(4)));

constexpr float cEPS = 1e-5f;
constexpr float cSLOPE = 0.2f;

__device__ __forceinline__ unsigned short f2b(float f){
  unsigned u = __float_as_uint(f);
  u = (u + 0x7fffu + ((u >> 16) & 1u)) >> 16;
  return (unsigned short)u;
}
__device__ __forceinline__ float b2f(unsigned short b){
  return __uint_as_float(((unsigned)b) << 16);
}

// ---------------- preprocessing ----------------
__global__ void k_f32_to_bf16(const float* __restrict__ in, unsigned short* __restrict__ out, int n4){
  int i = blockIdx.x * 256 + threadIdx.x;
  if(i >= n4) return;
  float4 v = ((const float4*)in)[i];
  ushort4 o = { f2b(v.x), f2b(v.y), f2b(v.z), f2b(v.w) };
  ((ushort4*)out)[i] = o;
}

__global__ void k_build_wt(const float* __restrict__ Wl, const float* __restrict__ Wr,
                           const float* __restrict__ skW, const float* __restrict__ pjW,
                           unsigned short* __restrict__ wt){
  int idx = blockIdx.x * 256 + threadIdx.x;
  if(idx >= 19 * 16384) return;
  int mat = idx >> 14, r = idx & 16383;
  int n = r >> 7, k = r & 127;
  const float* src;
  if(mat < 8)       src = Wl + mat * 16384;
  else if(mat < 16) src = Wr + (mat - 8) * 16384;
  else if(mat < 18) src = skW + (mat - 16) * 16384;
  else              src = pjW;
  wt[idx] = f2b(src[k * 128 + n]);
}

// ---------------- counting sort by key = dst*4 + ea ----------------
__global__ void k_hist_key(const int* __restrict__ dst, const int* __restrict__ ea,
                           unsigned int* __restrict__ cnt, int E){
  int i = blockIdx.x * 256 + threadIdx.x;
  if(i < E) atomicAdd(cnt + (dst[i]*4 + ea[i]), 1u);
}

__device__ __forceinline__ unsigned wave_iscan(unsigned v, int lane){
  #pragma unroll
  for(int ofs = 1; ofs < 64; ofs <<= 1){
    unsigned y = __shfl_up(v, ofs);
    if(lane >= ofs) v += y;
  }
  return v;  // inclusive scan across 64 lanes
}

// hierarchical exclusive scan: stage 1 — 4096 bins/block
__global__ __launch_bounds__(256) void k_scan_partial(
    const unsigned int* __restrict__ cnt, unsigned int* __restrict__ off,
    unsigned int* __restrict__ bsum, int n){
  __shared__ unsigned int buf[4096];
  __shared__ unsigned int wofs[4];
  const int base = blockIdx.x * 4096;
  for(int i = threadIdx.x; i < 4096; i += 256){
    int idx = base + i;
    buf[i] = (idx < n) ? cnt[idx] : 0u;
  }
  __syncthreads();
  const int lane = threadIdx.x & 63, wid = threadIdx.x >> 6;
  const int b = threadIdx.x * 16;
  unsigned loc[16]; unsigned s = 0;
  #pragma unroll
  for(int i = 0; i < 16; ++i){ loc[i] = s; s += buf[b + i]; }
  unsigned isc = wave_iscan(s, lane);
  unsigned texc = isc - s;              // exclusive within wave
  if(lane == 63) wofs[wid] = isc;       // wave total
  __syncthreads();
  unsigned wbase = 0;
  for(int w = 0; w < wid; ++w) wbase += wofs[w];
  unsigned tbase = wbase + texc;
  #pragma unroll
  for(int i = 0; i < 16; ++i){
    int idx = base + b + i;
    if(idx < n) off[idx] = tbase + loc[i];
  }
  if(threadIdx.x == 255) bsum[blockIdx.x] = wbase + isc;  // block total
}

// stage 2 — scan block totals (nblk <= 64), write grand total to off[n]
__global__ void k_scan_bsum(unsigned int* __restrict__ bsum, unsigned int* __restrict__ off,
                            int nblk, int n){
  if(threadIdx.x == 0 && blockIdx.x == 0){
    unsigned acc = 0;
    for(int i = 0; i < nblk; ++i){ unsigned v = bsum[i]; bsum[i] = acc; acc += v; }
    off[n] = acc;
  }
}

// stage 3 — add block base; also produce cursor copy for scatter
__global__ void k_scan_add(unsigned int* __restrict__ off, unsigned int* __restrict__ cur,
                           const unsigned int* __restrict__ bsum, int n){
  int i = blockIdx.x * 256 + threadIdx.x;
  if(i < n){
    unsigned v = off[i] + bsum[i >> 12];
    off[i] = v;
    cur[i] = v;
  }
}

__global__ void k_scatter_key(const int* __restrict__ dst, const int* __restrict__ ea,
                              const int* __restrict__ src,
                              unsigned int* __restrict__ cursor,
                              int* __restrict__ psrc, int E){
  int i = blockIdx.x * 256 + threadIdx.x;
  if(i < E){
    unsigned int pos = atomicAdd(cursor + (dst[i]*4 + ea[i]), 1u);
    psrc[pos] = src[i];
  }
}

// ---------------- GEMM ----------------
template<bool OUT_BF16>
__global__ __launch_bounds__(256) void k_gemm(
    const unsigned short* __restrict__ A, int M,
    const unsigned short* __restrict__ wtBase, long wtStride,
    const float* __restrict__ biasBase, int biasStride,
    void* __restrict__ outBase, long outStride)
{
  const unsigned short* Wt = wtBase + (long)blockIdx.y * wtStride;
  const float* bias = biasBase + (long)blockIdx.y * biasStride;
  const int wave = threadIdx.x >> 6, lane = threadIdx.x & 63;
  const int l16 = lane & 15, lhi = lane >> 4;

  bf16x8 bfr[8][4];
  #pragma unroll
  for(int cb = 0; cb < 8; ++cb)
    #pragma unroll
    for(int kb = 0; kb < 4; ++kb)
      bfr[cb][kb] = *(const bf16x8*)(Wt + (cb*16 + l16)*128 + kb*32 + lhi*8);

  const int row0 = blockIdx.x * 64 + wave * 16;
  const int arow = row0 + l16;
  const bf16x8 zf = {0,0,0,0,0,0,0,0};
  bf16x8 afr[4];
  if(arow < M){
    #pragma unroll
    for(int kb = 0; kb < 4; ++kb)
      afr[kb] = *(const bf16x8*)(A + (long)arow*128 + kb*32 + lhi*8);
  } else {
    #pragma unroll
    for(int kb = 0; kb < 4; ++kb) afr[kb] = zf;
  }

  const f32x4 z4 = {0.f,0.f,0.f,0.f};
  f32x4 acc[8];
  #pragma unroll
  for(int cb = 0; cb < 8; ++cb) acc[cb] = z4;
  #pragma unroll
  for(int cb = 0; cb < 8; ++cb)
    #pragma unroll
    for(int kb = 0; kb < 4; ++kb)
      acc[cb] = __builtin_amdgcn_mfma_f32_16x16x32_bf16(afr[kb], bfr[cb][kb], acc[cb], 0, 0, 0);

  #pragma unroll
  for(int cb = 0; cb < 8; ++cb){
    int col = cb*16 + l16;
    float bv = bias[col];
    #pragma unroll
    for(int q = 0; q < 4; ++q){
      int rrow = row0 + lhi*4 + q;
      if(rrow < M){
        float v = acc[cb][q] + bv;
        long oidx = (long)blockIdx.y * outStride + (long)rrow * 128 + col;
        if(OUT_BF16) ((unsigned short*)outBase)[oidx] = f2b(v);
        else         ((float*)outBase)[oidx] = v;
      }
    }
  }
}

// ---------------- per-dst fused attention+aggregate+BN (uniform r, online softmax) ----------------
__global__ __launch_bounds__(64) void k_dst_agg(
    const unsigned int* __restrict__ off, const int* __restrict__ psrc,
    const unsigned short* __restrict__ xl, const unsigned short* __restrict__ xr,
    const float* __restrict__ att,
    const float* __restrict__ conv_b, const float* __restrict__ bn_g, const float* __restrict__ bn_b,
    const float* __restrict__ bn_m, const float* __restrict__ bn_v,
    float* __restrict__ out, int N, int nt)
{
  const int t = blockIdx.x;
  const int lane = threadIdx.x;
  const int sub  = lane >> 4;
  const int l16  = lane & 15;

  float4 o0 = ((const float4*)(out + (long)t*128 + l16*8))[0];
  float4 o1 = ((const float4*)(out + (long)t*128 + l16*8))[1];
  float oc[8] = {o0.x,o0.y,o0.z,o0.w,o1.x,o1.y,o1.z,o1.w};

  for(int r = 0; r < 4; ++r){                      // r is WAVE-UNIFORM -> all reg indices static
    const bf16x8 xrv = *(const bf16x8*)(xr + ((long)r*nt + t)*128 + l16*8);
    const float4 a0 = ((const float4*)(att + r*128 + l16*8))[0];
    const float4 a1 = ((const float4*)(att + r*128 + l16*8))[1];
    const float av[8] = {a0.x,a0.y,a0.z,a0.w,a1.x,a1.y,a1.z,a1.w};
    float xrf[8];
    #pragma unroll
    for(int q = 0; q < 8; ++q) xrf[q] = b2f((unsigned short)xrv[q]);

    const unsigned s0 = off[t*4 + r], s1 = off[t*4 + r + 1];

    float m = -3.0e38f, den = 0.f;
    float acc[8];
    #pragma unroll
    for(int q = 0; q < 8; ++q) acc[q] = 0.f;

    for(unsigned e = s0 + sub; e < s1; e += 4){
      int s = psrc[e];
      bf16x8 xlv = *(const bf16x8*)(xl + ((long)r*N + s)*128 + l16*8);
      float xlf[8];
      #pragma unroll
      for(int q = 0; q < 8; ++q) xlf[q] = b2f((unsigned short)xlv[q]);
      float part = 0.f;
      #pragma unroll
      for(int q = 0; q < 8; ++q){
        float v = xlf[q] + xrf[q];
        v = v >= 0.f ? v : cSLOPE * v;
        part += v * av[q];
      }
      part += __shfl_xor(part, 1);
      part += __shfl_xor(part, 2);      // all 4 lanes of the quad now hold head logit
      float nm = fmaxf(m, part);
      float corr = __expf(m - nm);
      float p = __expf(part - nm);
      den = den * corr + p;
      #pragma unroll
      for(int q = 0; q < 8; ++q) acc[q] = acc[q] * corr + p * xlf[q];
      m = nm;
    }

    // merge the 4 edge-slots (lanes differing in bits 4,5)
    #pragma unroll
    for(int ofs = 16; ofs <= 32; ofs <<= 1){
      float m2 = __shfl_xor(m, ofs);
      float d2 = __shfl_xor(den, ofs);
      float M = fmaxf(m, m2);
      float sA = __expf(m - M), sB = __expf(m2 - M);
      den = den * sA + d2 * sB;
      #pragma unroll
      for(int q = 0; q < 8; ++q){
        float a2 = __shfl_xor(acc[q], ofs);
        acc[q] = acc[q] * sA + a2 * sB;
      }
      m = M;
    }

    const float inv = 1.f / fmaxf(den, 1e-16f);
    const float4 cb0 = ((const float4*)(conv_b + r*128 + l16*8))[0];
    const float4 cb1 = ((const float4*)(conv_b + r*128 + l16*8))[1];
    const float4 gg0 = ((const float4*)(bn_g  + r*128 + l16*8))[0];
    const float4 gg1 = ((const float4*)(bn_g  + r*128 + l16*8))[1];
    const float4 bb0 = ((const float4*)(bn_b  + r*128 + l16*8))[0];
    const float4 bb1 = ((const float4*)(bn_b  + r*128 + l16*8))[1];
    const float4 mm0 = ((const float4*)(bn_m  + r*128 + l16*8))[0];
    const float4 mm1 = ((const float4*)(bn_m  + r*128 + l16*8))[1];
    const float4 vv0 = ((const float4*)(bn_v  + r*128 + l16*8))[0];
    const float4 vv1 = ((const float4*)(bn_v  + r*128 + l16*8))[1];
    const float cbv[8] = {cb0.x,cb0.y,cb0.z,cb0.w,cb1.x,cb1.y,cb1.z,cb1.w};
    const float ggv[8] = {gg0.x,gg0.y,gg0.z,gg0.w,gg1.x,gg1.y,gg1.z,gg1.w};
    const float bbv[8] = {bb0.x,bb0.y,bb0.z,bb0.w,bb1.x,bb1.y,bb1.z,bb1.w};
    const float mmv[8] = {mm0.x,mm0.y,mm0.z,mm0.w,mm1.x,mm1.y,mm1.z,mm1.w};
    const float vvv[8] = {vv0.x,vv0.y,vv0.z,vv0.w,vv1.x,vv1.y,vv1.z,vv1.w};
    #pragma unroll
    for(int q = 0; q < 8; ++q)
      oc[q] += (acc[q] * inv + cbv[q] - mmv[q]) * rsqrtf(vvv[q] + cEPS) * ggv[q] + bbv[q];
  }

  if(sub == 0){
    float4 w0 = {oc[0],oc[1],oc[2],oc[3]}, w1 = {oc[4],oc[5],oc[6],oc[7]};
    ((float4*)(out + (long)t*128 + l16*8))[0] = w0;
    ((float4*)(out + (long)t*128 + l16*8))[1] = w1;
  }
}

// ---------------- ELU ----------------
__global__ void k_elu_act(const float* __restrict__ in, unsigned short* __restrict__ outBf,
                          float* __restrict__ outF32, int n4){
  int i = blockIdx.x * 256 + threadIdx.x;
  if(i >= n4) return;
  float4 v = ((const float4*)in)[i];
  float4 e;
  e.x = v.x > 0.f ? v.x : __expf(v.x) - 1.f;
  e.y = v.y > 0.f ? v.y : __expf(v.y) - 1.f;
  e.z = v.z > 0.f ? v.z : __expf(v.z) - 1.f;
  e.w = v.w > 0.f ? v.w : __expf(v.w) - 1.f;
  ushort4 o = { f2b(e.x), f2b(e.y), f2b(e.z), f2b(e.w) };
  ((ushort4*)outBf)[i] = o;
  if(outF32) ((float4*)outF32)[i] = e;
}

// ---------------- projection BN + PReLU ----------------
__global__ void k_pbn_prelu(float* __restrict__ hbuf, const float* __restrict__ g, const float* __restrict__ b,
                            const float* __restrict__ m, const float* __restrict__ v,
                            const float* __restrict__ a, int n4){
  int i = blockIdx.x * 256 + threadIdx.x;
  if(i >= n4) return;
  int c4 = i & 31;
  float4 x  = ((const float4*)hbuf)[i];
  float4 gg = ((const float4*)g)[c4], bb = ((const float4*)b)[c4];
  float4 mm = ((const float4*)m)[c4], vv = ((const float4*)v)[c4];
  float al = a[0];
  float4 y;
  y.x = (x.x - mm.x) * rsqrtf(vv.x + cEPS) * gg.x + bb.x; y.x = y.x > 0.f ? y.x : al * y.x;
  y.y = (x.y - mm.y) * rsqrtf(vv.y + cEPS) * gg.y + bb.y; y.y = y.y > 0.f ? y.y : al * y.y;
  y.z = (x.z - mm.z) * rsqrtf(vv.z + cEPS) * gg.z + bb.z; y.z = y.z > 0.f ? y.z : al * y.z;
  y.w = (x.w - mm.w) * rsqrtf(vv.w + cEPS) * gg.w + bb.w; y.w = y.w > 0.f ? y.w : al * y.w;
  ((float4*)hbuf)[i] = y;
}

extern "C" void kernel_launch(void* const* d_in, const int* in_sizes, int n_in,
                              void* d_out, int out_size, void* d_ws, size_t ws_size,
                              hipStream_t stream)
{
  const float* x0     = (const float*)d_in[0];
  const int*   src0   = (const int*)d_in[1];
  const int*   dst0   = (const int*)d_in[2];
  const int*   ea0    = (const int*)d_in[3];
  const int*   src1   = (const int*)d_in[4];
  const int*   dst1   = (const int*)d_in[5];
  const int*   ea1    = (const int*)d_in[6];
  const float* Wl     = (const float*)d_in[7];
  const float* Wr     = (const float*)d_in[8];
  const float* bl     = (const float*)d_in[9];
  const float* br     = (const float*)d_in[10];
  const float* att    = (const float*)d_in[11];
  const float* conv_b = (const float*)d_in[12];
  const float* bn_g   = (const float*)d_in[13];
  const float* bn_b   = (const float*)d_in[14];
  const float* bn_m   = (const float*)d_in[15];
  const float* bn_v   = (const float*)d_in[16];
  const float* skip_W = (const float*)d_in[17];
  const float* skip_b = (const float*)d_in[18];
  const float* proj_W = (const float*)d_in[19];
  const float* proj_b = (const float*)d_in[20];
  const float* pbn_g  = (const float*)d_in[21];
  const float* pbn_b  = (const float*)d_in[22];
  const float* pbn_m  = (const float*)d_in[23];
  const float* pbn_v  = (const float*)d_in[24];
  const float* prelu_a= (const float*)d_in[25];

  const int N0 = in_sizes[0] / 128;
  const int E0 = in_sizes[1];
  const int E1 = in_sizes[4];
  const int N1 = 30000;
  const int N2 = 8000;
  const int jc = 4;

  auto al = [](size_t x){ return (x + 255) & ~(size_t)255; };
  char* p = (char*)d_ws;
  auto carve = [&](size_t bytes){ char* r = p; p += al(bytes); return r; };
  unsigned short* wt    = (unsigned short*)carve((size_t)19*16384*2);
  unsigned short* xbf   = (unsigned short*)carve((size_t)N0*256);
  unsigned short* xlb   = (unsigned short*)carve((size_t)jc*N0*256);
  unsigned short* xrb   = (unsigned short*)carve((size_t)jc*N1*256);
  unsigned int*   cnt   = (unsigned int*)carve((size_t)(N1*4+1)*4);
  unsigned int*   off   = (unsigned int*)carve((size_t)(N1*4+1)*4);
  unsigned int*   cur   = (unsigned int*)carve((size_t)(N1*4+1)*4);
  unsigned int*   bsum  = (unsigned int*)carve((size_t)256*4);
  int*            psrc  = (int*)carve((size_t)E0*4);
  float*          out1  = (float*)carve((size_t)N1*512);

  k_f32_to_bf16<<<(N0*32 + 255)/256, 256, 0, stream>>>(x0, xbf, N0*32);
  k_build_wt<<<(19*16384 + 255)/256, 256, 0, stream>>>(Wl, Wr, skip_W, proj_W, wt);

  auto run_layer = [&](int li, int N, int nt, const int* src, const int* dst, const int* ea, int E){
    const int nbins = nt * 4;
    const int nblk = (nbins + 4095) / 4096;
    hipMemsetAsync(cnt, 0, (size_t)(nbins + 1) * 4, stream);
    k_hist_key<<<(E + 255)/256, 256, 0, stream>>>(dst, ea, cnt, E);
    k_scan_partial<<<nblk, 256, 0, stream>>>(cnt, off, bsum, nbins);
    k_scan_bsum<<<1, 64, 0, stream>>>(bsum, off, nblk, nbins);
    k_scan_add<<<(nbins + 255)/256, 256, 0, stream>>>(off, cur, bsum, nbins);
    k_scatter_key<<<(E + 255)/256, 256, 0, stream>>>(dst, ea, src, cur, psrc, E);

    k_gemm<false><<<dim3((nt+63)/64, 1), 256, 0, stream>>>(
        xbf, nt, wt + (16+li)*16384, 0, skip_b + li*128, 0, out1, 0);
    k_gemm<true><<<dim3((N+63)/64, jc), 256, 0, stream>>>(
        xbf, N,  wt + (li*4)*16384,   16384, bl + (li*4)*128, 128, xlb, (long)N*128);
    k_gemm<true><<<dim3((nt+63)/64, jc), 256, 0, stream>>>(
        xbf, nt, wt + (8+li*4)*16384, 16384, br + (li*4)*128, 128, xrb, (long)nt*128);
    k_dst_agg<<<nt, 64, 0, stream>>>(
        off, psrc, xlb, xrb, att + li*512,
        conv_b + li*512, bn_g + li*512, bn_b + li*512, bn_m + li*512, bn_v + li*512,
        out1, N, nt);
  };

  run_layer(0, N0, N1, src0, dst0, ea0, E0);
  k_elu_act<<<(N1*32 + 255)/256, 256, 0, stream>>>(out1, xbf, nullptr, N1*32);
  run_layer(1, N1, N2, src1, dst1, ea1, E1);

  float* outX = (float*)d_out;
  float* outP = (float*)d_out + (size_t)N2*128;
  k_elu_act<<<(N2*32 + 255)/256, 256, 0, stream>>>(out1, xbf, outX, N2*32);
  k_gemm<false><<<dim3((N2+63)/64, 1), 256, 0, stream>>>(
      xbf, N2, wt + 18*16384, 0, proj_b, 0, outP, 0);
  k_pbn_prelu<<<(N2*32 + 255)/256, 256, 0, stream>>>(outP, pbn_g, pbn_b, pbn_m, pbn_v, prelu_a, N2*32);
}

// Round 10
// 486.733 us; speedup vs baseline: 2.6109x; 1.3660x over previous
//
#include <hip/hip_runtime.h>
#include <stdint.h>

typedef short bf16x8 __attribute__((ext_vector_type(8)));
typedef float f32x4 __attribute__((ext_vector_type(4)));

constexpr float cEPS = 1e-5f;
constexpr float cSLOPE = 0.2f;

__device__ __forceinline__ unsigned short f2b(float f){
  unsigned u = __float_as_uint(f);
  u = (u + 0x7fffu + ((u >> 16) & 1u)) >> 16;
  return (unsigned short)u;
}
__device__ __forceinline__ float b2f(unsigned short b){
  return __uint_as_float(((unsigned)b) << 16);
}

// ---------------- preprocessing ----------------
// 8 bf16 out per thread (32B in, 16B out)
__global__ void k_f32_to_bf16(const float* __restrict__ in, unsigned short* __restrict__ out, int n8){
  int i = blockIdx.x * 256 + threadIdx.x;
  if(i >= n8) return;
  float4 v0 = ((const float4*)in)[i*2];
  float4 v1 = ((const float4*)in)[i*2 + 1];
  bf16x8 o = { (short)f2b(v0.x), (short)f2b(v0.y), (short)f2b(v0.z), (short)f2b(v0.w),
               (short)f2b(v1.x), (short)f2b(v1.y), (short)f2b(v1.z), (short)f2b(v1.w) };
  ((bf16x8*)out)[i] = o;
}

__global__ void k_build_wt(const float* __restrict__ Wl, const float* __restrict__ Wr,
                           const float* __restrict__ skW, const float* __restrict__ pjW,
                           unsigned short* __restrict__ wt){
  int idx = blockIdx.x * 256 + threadIdx.x;
  if(idx >= 19 * 16384) return;
  int mat = idx >> 14, r = idx & 16383;
  int n = r >> 7, k = r & 127;
  const float* src;
  if(mat < 8)       src = Wl + mat * 16384;
  else if(mat < 16) src = Wr + (mat - 8) * 16384;
  else if(mat < 18) src = skW + (mat - 16) * 16384;
  else              src = pjW;
  wt[idx] = f2b(src[k * 128 + n]);
}

// ---------------- counting sort by key = dst*4 + ea ----------------
__global__ void k_hist_key(const int* __restrict__ dst, const int* __restrict__ ea,
                           unsigned int* __restrict__ cnt, int E){
  int i = blockIdx.x * 256 + threadIdx.x;
  if(i < E) atomicAdd(cnt + (dst[i]*4 + ea[i]), 1u);
}

__device__ __forceinline__ unsigned wave_iscan(unsigned v, int lane){
  #pragma unroll
  for(int ofs = 1; ofs < 64; ofs <<= 1){
    unsigned y = __shfl_up(v, ofs);
    if(lane >= ofs) v += y;
  }
  return v;  // inclusive scan across 64 lanes
}

// hierarchical exclusive scan: stage 1 — 4096 bins/block
__global__ __launch_bounds__(256) void k_scan_partial(
    const unsigned int* __restrict__ cnt, unsigned int* __restrict__ off,
    unsigned int* __restrict__ bsum, int n){
  __shared__ unsigned int buf[4096];
  __shared__ unsigned int wofs[4];
  const int base = blockIdx.x * 4096;
  for(int i = threadIdx.x; i < 4096; i += 256){
    int idx = base + i;
    buf[i] = (idx < n) ? cnt[idx] : 0u;
  }
  __syncthreads();
  const int lane = threadIdx.x & 63, wid = threadIdx.x >> 6;
  const int b = threadIdx.x * 16;
  unsigned loc[16]; unsigned s = 0;
  #pragma unroll
  for(int i = 0; i < 16; ++i){ loc[i] = s; s += buf[b + i]; }
  unsigned isc = wave_iscan(s, lane);
  unsigned texc = isc - s;              // exclusive within wave
  if(lane == 63) wofs[wid] = isc;       // wave total
  __syncthreads();
  unsigned wbase = 0;
  for(int w = 0; w < wid; ++w) wbase += wofs[w];
  unsigned tbase = wbase + texc;
  #pragma unroll
  for(int i = 0; i < 16; ++i){
    int idx = base + b + i;
    if(idx < n) off[idx] = tbase + loc[i];
  }
  if(threadIdx.x == 255) bsum[blockIdx.x] = wbase + isc;  // block total
}

// stage 2 — scan block totals (nblk <= 64), write grand total to off[n]
__global__ void k_scan_bsum(unsigned int* __restrict__ bsum, unsigned int* __restrict__ off,
                            int nblk, int n){
  if(threadIdx.x == 0 && blockIdx.x == 0){
    unsigned acc = 0;
    for(int i = 0; i < nblk; ++i){ unsigned v = bsum[i]; bsum[i] = acc; acc += v; }
    off[n] = acc;
  }
}

// stage 3 — add block base; also produce cursor copy for scatter
__global__ void k_scan_add(unsigned int* __restrict__ off, unsigned int* __restrict__ cur,
                           const unsigned int* __restrict__ bsum, int n){
  int i = blockIdx.x * 256 + threadIdx.x;
  if(i < n){
    unsigned v = off[i] + bsum[i >> 12];
    off[i] = v;
    cur[i] = v;
  }
}

__global__ void k_scatter_key(const int* __restrict__ dst, const int* __restrict__ ea,
                              const int* __restrict__ src,
                              unsigned int* __restrict__ cursor,
                              int* __restrict__ psrc, int E){
  int i = blockIdx.x * 256 + threadIdx.x;
  if(i < E){
    unsigned int pos = atomicAdd(cursor + (dst[i]*4 + ea[i]), 1u);
    psrc[pos] = src[i];
  }
}

// ---------------- GEMM (Wt staged in LDS, padded stride 136) ----------------
// out[M,128] = A[M,128] @ W + bias. Wt is (N,K) row-major. blockIdx.y = relation.
// LDS: 128 rows x 136 bf16 (16B pad/row -> fragment reads spread 8 banks, ~2-way).
template<bool OUT_BF16>
__global__ __launch_bounds__(256) void k_gemm(
    const unsigned short* __restrict__ A, int M,
    const unsigned short* __restrict__ wtBase, long wtStride,
    const float* __restrict__ biasBase, int biasStride,
    void* __restrict__ outBase, long outStride)
{
  __shared__ unsigned short lw[128 * 136];
  const unsigned short* Wt = wtBase + (long)blockIdx.y * wtStride;
  #pragma unroll
  for(int it = 0; it < 8; ++it){
    int idx = it * 256 + threadIdx.x;     // 0..2047
    int row = idx >> 4, c8 = idx & 15;
    bf16x8 v = *(const bf16x8*)(Wt + row * 128 + c8 * 8);
    *(bf16x8*)(lw + row * 136 + c8 * 8) = v;
  }

  const float* bias = biasBase + (long)blockIdx.y * biasStride;
  const int wave = threadIdx.x >> 6, lane = threadIdx.x & 63;
  const int l16 = lane & 15, lhi = lane >> 4;

  const int row0 = blockIdx.x * 64 + wave * 16;
  const int arow = row0 + l16;
  const bf16x8 zf = {0,0,0,0,0,0,0,0};
  bf16x8 afr[4];
  if(arow < M){
    #pragma unroll
    for(int kb = 0; kb < 4; ++kb)
      afr[kb] = *(const bf16x8*)(A + (long)arow*128 + kb*32 + lhi*8);
  } else {
    #pragma unroll
    for(int kb = 0; kb < 4; ++kb) afr[kb] = zf;
  }
  __syncthreads();

  const f32x4 z4 = {0.f,0.f,0.f,0.f};
  f32x4 acc[8];
  #pragma unroll
  for(int cb = 0; cb < 8; ++cb) acc[cb] = z4;
  #pragma unroll
  for(int cb = 0; cb < 8; ++cb){
    #pragma unroll
    for(int kb = 0; kb < 4; ++kb){
      bf16x8 bfr = *(const bf16x8*)(lw + (cb*16 + l16)*136 + kb*32 + lhi*8);
      acc[cb] = __builtin_amdgcn_mfma_f32_16x16x32_bf16(afr[kb], bfr, acc[cb], 0, 0, 0);
    }
  }

  #pragma unroll
  for(int cb = 0; cb < 8; ++cb){
    int col = cb*16 + l16;
    float bv = bias[col];
    #pragma unroll
    for(int q = 0; q < 4; ++q){
      int rrow = row0 + lhi*4 + q;
      if(rrow < M){
        float v = acc[cb][q] + bv;
        long oidx = (long)blockIdx.y * outStride + (long)rrow * 128 + col;
        if(OUT_BF16) ((unsigned short*)outBase)[oidx] = f2b(v);
        else         ((float*)outBase)[oidx] = v;
      }
    }
  }
}

// ---------------- per-dst fused attention+aggregate+BN (uniform r, online softmax) ----------------
__global__ __launch_bounds__(64) void k_dst_agg(
    const unsigned int* __restrict__ off, const int* __restrict__ psrc,
    const unsigned short* __restrict__ xl, const unsigned short* __restrict__ xr,
    const float* __restrict__ att,
    const float* __restrict__ conv_b, const float* __restrict__ bn_g, const float* __restrict__ bn_b,
    const float* __restrict__ bn_m, const float* __restrict__ bn_v,
    float* __restrict__ out, int N, int nt)
{
  const int t = blockIdx.x;
  const int lane = threadIdx.x;
  const int sub  = lane >> 4;
  const int l16  = lane & 15;

  float4 o0 = ((const float4*)(out + (long)t*128 + l16*8))[0];
  float4 o1 = ((const float4*)(out + (long)t*128 + l16*8))[1];
  float oc[8] = {o0.x,o0.y,o0.z,o0.w,o1.x,o1.y,o1.z,o1.w};

  for(int r = 0; r < 4; ++r){                      // r is WAVE-UNIFORM -> all reg indices static
    const bf16x8 xrv = *(const bf16x8*)(xr + ((long)r*nt + t)*128 + l16*8);
    const float4 a0 = ((const float4*)(att + r*128 + l16*8))[0];
    const float4 a1 = ((const float4*)(att + r*128 + l16*8))[1];
    const float av[8] = {a0.x,a0.y,a0.z,a0.w,a1.x,a1.y,a1.z,a1.w};
    float xrf[8];
    #pragma unroll
    for(int q = 0; q < 8; ++q) xrf[q] = b2f((unsigned short)xrv[q]);

    const unsigned s0 = off[t*4 + r], s1 = off[t*4 + r + 1];

    float m = -3.0e38f, den = 0.f;
    float acc[8];
    #pragma unroll
    for(int q = 0; q < 8; ++q) acc[q] = 0.f;

    for(unsigned e = s0 + sub; e < s1; e += 4){
      int s = psrc[e];
      bf16x8 xlv = *(const bf16x8*)(xl + ((long)r*N + s)*128 + l16*8);
      float xlf[8];
      #pragma unroll
      for(int q = 0; q < 8; ++q) xlf[q] = b2f((unsigned short)xlv[q]);
      float part = 0.f;
      #pragma unroll
      for(int q = 0; q < 8; ++q){
        float v = xlf[q] + xrf[q];
        v = v >= 0.f ? v : cSLOPE * v;
        part += v * av[q];
      }
      part += __shfl_xor(part, 1);
      part += __shfl_xor(part, 2);      // all 4 lanes of the quad now hold head logit
      float nm = fmaxf(m, part);
      float corr = __expf(m - nm);
      float p = __expf(part - nm);
      den = den * corr + p;
      #pragma unroll
      for(int q = 0; q < 8; ++q) acc[q] = acc[q] * corr + p * xlf[q];
      m = nm;
    }

    // merge the 4 edge-slots (lanes differing in bits 4,5)
    #pragma unroll
    for(int ofs = 16; ofs <= 32; ofs <<= 1){
      float m2 = __shfl_xor(m, ofs);
      float d2 = __shfl_xor(den, ofs);
      float M = fmaxf(m, m2);
      float sA = __expf(m - M), sB = __expf(m2 - M);
      den = den * sA + d2 * sB;
      #pragma unroll
      for(int q = 0; q < 8; ++q){
        float a2 = __shfl_xor(acc[q], ofs);
        acc[q] = acc[q] * sA + a2 * sB;
      }
      m = M;
    }

    const float inv = 1.f / fmaxf(den, 1e-16f);
    const float4 cb0 = ((const float4*)(conv_b + r*128 + l16*8))[0];
    const float4 cb1 = ((const float4*)(conv_b + r*128 + l16*8))[1];
    const float4 gg0 = ((const float4*)(bn_g  + r*128 + l16*8))[0];
    const float4 gg1 = ((const float4*)(bn_g  + r*128 + l16*8))[1];
    const float4 bb0 = ((const float4*)(bn_b  + r*128 + l16*8))[0];
    const float4 bb1 = ((const float4*)(bn_b  + r*128 + l16*8))[1];
    const float4 mm0 = ((const float4*)(bn_m  + r*128 + l16*8))[0];
    const float4 mm1 = ((const float4*)(bn_m  + r*128 + l16*8))[1];
    const float4 vv0 = ((const float4*)(bn_v  + r*128 + l16*8))[0];
    const float4 vv1 = ((const float4*)(bn_v  + r*128 + l16*8))[1];
    const float cbv[8] = {cb0.x,cb0.y,cb0.z,cb0.w,cb1.x,cb1.y,cb1.z,cb1.w};
    const float ggv[8] = {gg0.x,gg0.y,gg0.z,gg0.w,gg1.x,gg1.y,gg1.z,gg1.w};
    const float bbv[8] = {bb0.x,bb0.y,bb0.z,bb0.w,bb1.x,bb1.y,bb1.z,bb1.w};
    const float mmv[8] = {mm0.x,mm0.y,mm0.z,mm0.w,mm1.x,mm1.y,mm1.z,mm1.w};
    const float vvv[8] = {vv0.x,vv0.y,vv0.z,vv0.w,vv1.x,vv1.y,vv1.z,vv1.w};
    #pragma unroll
    for(int q = 0; q < 8; ++q)
      oc[q] += (acc[q] * inv + cbv[q] - mmv[q]) * rsqrtf(vvv[q] + cEPS) * ggv[q] + bbv[q];
  }

  if(sub == 0){
    float4 w0 = {oc[0],oc[1],oc[2],oc[3]}, w1 = {oc[4],oc[5],oc[6],oc[7]};
    ((float4*)(out + (long)t*128 + l16*8))[0] = w0;
    ((float4*)(out + (long)t*128 + l16*8))[1] = w1;
  }
}

// ---------------- ELU ----------------
__global__ void k_elu_act(const float* __restrict__ in, unsigned short* __restrict__ outBf,
                          float* __restrict__ outF32, int n4){
  int i = blockIdx.x * 256 + threadIdx.x;
  if(i >= n4) return;
  float4 v = ((const float4*)in)[i];
  float4 e;
  e.x = v.x > 0.f ? v.x : __expf(v.x) - 1.f;
  e.y = v.y > 0.f ? v.y : __expf(v.y) - 1.f;
  e.z = v.z > 0.f ? v.z : __expf(v.z) - 1.f;
  e.w = v.w > 0.f ? v.w : __expf(v.w) - 1.f;
  ushort4 o = { f2b(e.x), f2b(e.y), f2b(e.z), f2b(e.w) };
  ((ushort4*)outBf)[i] = o;
  if(outF32) ((float4*)outF32)[i] = e;
}

// ---------------- projection BN + PReLU ----------------
__global__ void k_pbn_prelu(float* __restrict__ hbuf, const float* __restrict__ g, const float* __restrict__ b,
                            const float* __restrict__ m, const float* __restrict__ v,
                            const float* __restrict__ a, int n4){
  int i = blockIdx.x * 256 + threadIdx.x;
  if(i >= n4) return;
  int c4 = i & 31;
  float4 x  = ((const float4*)hbuf)[i];
  float4 gg = ((const float4*)g)[c4], bb = ((const float4*)b)[c4];
  float4 mm = ((const float4*)m)[c4], vv = ((const float4*)v)[c4];
  float al = a[0];
  float4 y;
  y.x = (x.x - mm.x) * rsqrtf(vv.x + cEPS) * gg.x + bb.x; y.x = y.x > 0.f ? y.x : al * y.x;
  y.y = (x.y - mm.y) * rsqrtf(vv.y + cEPS) * gg.y + bb.y; y.y = y.y > 0.f ? y.y : al * y.y;
  y.z = (x.z - mm.z) * rsqrtf(vv.z + cEPS) * gg.z + bb.z; y.z = y.z > 0.f ? y.z : al * y.z;
  y.w = (x.w - mm.w) * rsqrtf(vv.w + cEPS) * gg.w + bb.w; y.w = y.w > 0.f ? y.w : al * y.w;
  ((float4*)hbuf)[i] = y;
}

extern "C" void kernel_launch(void* const* d_in, const int* in_sizes, int n_in,
                              void* d_out, int out_size, void* d_ws, size_t ws_size,
                              hipStream_t stream)
{
  const float* x0     = (const float*)d_in[0];
  const int*   src0   = (const int*)d_in[1];
  const int*   dst0   = (const int*)d_in[2];
  const int*   ea0    = (const int*)d_in[3];
  const int*   src1   = (const int*)d_in[4];
  const int*   dst1   = (const int*)d_in[5];
  const int*   ea1    = (const int*)d_in[6];
  const float* Wl     = (const float*)d_in[7];
  const float* Wr     = (const float*)d_in[8];
  const float* bl     = (const float*)d_in[9];
  const float* br     = (const float*)d_in[10];
  const float* att    = (const float*)d_in[11];
  const float* conv_b = (const float*)d_in[12];
  const float* bn_g   = (const float*)d_in[13];
  const float* bn_b   = (const float*)d_in[14];
  const float* bn_m   = (const float*)d_in[15];
  const float* bn_v   = (const float*)d_in[16];
  const float* skip_W = (const float*)d_in[17];
  const float* skip_b = (const float*)d_in[18];
  const float* proj_W = (const float*)d_in[19];
  const float* proj_b = (const float*)d_in[20];
  const float* pbn_g  = (const float*)d_in[21];
  const float* pbn_b  = (const float*)d_in[22];
  const float* pbn_m  = (const float*)d_in[23];
  const float* pbn_v  = (const float*)d_in[24];
  const float* prelu_a= (const float*)d_in[25];

  const int N0 = in_sizes[0] / 128;
  const int E0 = in_sizes[1];
  const int E1 = in_sizes[4];
  const int N1 = 30000;
  const int N2 = 8000;
  const int jc = 4;

  auto al = [](size_t x){ return (x + 255) & ~(size_t)255; };
  char* p = (char*)d_ws;
  auto carve = [&](size_t bytes){ char* r = p; p += al(bytes); return r; };
  unsigned short* wt    = (unsigned short*)carve((size_t)19*16384*2);
  unsigned short* xbf   = (unsigned short*)carve((size_t)N0*256);
  unsigned short* xlb   = (unsigned short*)carve((size_t)jc*N0*256);
  unsigned short* xrb   = (unsigned short*)carve((size_t)jc*N1*256);
  unsigned int*   cnt   = (unsigned int*)carve((size_t)(N1*4+1)*4);
  unsigned int*   off   = (unsigned int*)carve((size_t)(N1*4+1)*4);
  unsigned int*   cur   = (unsigned int*)carve((size_t)(N1*4+1)*4);
  unsigned int*   bsum  = (unsigned int*)carve((size_t)256*4);
  int*            psrc  = (int*)carve((size_t)E0*4);
  float*          out1  = (float*)carve((size_t)N1*512);

  k_f32_to_bf16<<<(N0*16 + 255)/256, 256, 0, stream>>>(x0, xbf, N0*16);
  k_build_wt<<<(19*16384 + 255)/256, 256, 0, stream>>>(Wl, Wr, skip_W, proj_W, wt);

  auto run_layer = [&](int li, int N, int nt, const int* src, const int* dst, const int* ea, int E){
    const int nbins = nt * 4;
    const int nblk = (nbins + 4095) / 4096;
    hipMemsetAsync(cnt, 0, (size_t)(nbins + 1) * 4, stream);
    k_hist_key<<<(E + 255)/256, 256, 0, stream>>>(dst, ea, cnt, E);
    k_scan_partial<<<nblk, 256, 0, stream>>>(cnt, off, bsum, nbins);
    k_scan_bsum<<<1, 64, 0, stream>>>(bsum, off, nblk, nbins);
    k_scan_add<<<(nbins + 255)/256, 256, 0, stream>>>(off, cur, bsum, nbins);
    k_scatter_key<<<(E + 255)/256, 256, 0, stream>>>(dst, ea, src, cur, psrc, E);

    k_gemm<false><<<dim3((nt+63)/64, 1), 256, 0, stream>>>(
        xbf, nt, wt + (16+li)*16384, 0, skip_b + li*128, 0, out1, 0);
    k_gemm<true><<<dim3((N+63)/64, jc), 256, 0, stream>>>(
        xbf, N,  wt + (li*4)*16384,   16384, bl + (li*4)*128, 128, xlb, (long)N*128);
    k_gemm<true><<<dim3((nt+63)/64, jc), 256, 0, stream>>>(
        xbf, nt, wt + (8+li*4)*16384, 16384, br + (li*4)*128, 128, xrb, (long)nt*128);
    k_dst_agg<<<nt, 64, 0, stream>>>(
        off, psrc, xlb, xrb, att + li*512,
        conv_b + li*512, bn_g + li*512, bn_b + li*512, bn_m + li*512, bn_v + li*512,
        out1, N, nt);
  };

  run_layer(0, N0, N1, src0, dst0, ea0, E0);
  k_elu_act<<<(N1*32 + 255)/256, 256, 0, stream>>>(out1, xbf, nullptr, N1*32);
  run_layer(1, N1, N2, src1, dst1, ea1, E1);

  float* outX = (float*)d_out;
  float* outP = (float*)d_out + (size_t)N2*128;
  k_elu_act<<<(N2*32 + 255)/256, 256, 0, stream>>>(out1, xbf, outX, N2*32);
  k_gemm<false><<<dim3((N2+63)/64, 1), 256, 0, stream>>>(
      xbf, N2, wt + 18*16384, 0, proj_b, 0, outP, 0);
  k_pbn_prelu<<<(N2*32 + 255)/256, 256, 0, stream>>>(outP, pbn_g, pbn_b, pbn_m, pbn_v, prelu_a, N2*32);
}

// Round 11
// 477.983 us; speedup vs baseline: 2.6587x; 1.0183x over previous
//
#include <hip/hip_runtime.h>
#include <stdint.h>

typedef short bf16x8 __attribute__((ext_vector_type(8)));
typedef float f32x4 __attribute__((ext_vector_type(4)));

constexpr float cEPS = 1e-5f;
constexpr float cSLOPE = 0.2f;

__device__ __forceinline__ unsigned short f2b(float f){
  unsigned u = __float_as_uint(f);
  u = (u + 0x7fffu + ((u >> 16) & 1u)) >> 16;
  return (unsigned short)u;
}
__device__ __forceinline__ float b2f(unsigned short b){
  return __uint_as_float(((unsigned)b) << 16);
}

// ---------------- preprocessing ----------------
// 8 bf16 out per thread (32B in, 16B out)
__global__ void k_f32_to_bf16(const float* __restrict__ in, unsigned short* __restrict__ out, int n8){
  int i = blockIdx.x * 256 + threadIdx.x;
  if(i >= n8) return;
  float4 v0 = ((const float4*)in)[i*2];
  float4 v1 = ((const float4*)in)[i*2 + 1];
  bf16x8 o = { (short)f2b(v0.x), (short)f2b(v0.y), (short)f2b(v0.z), (short)f2b(v0.w),
               (short)f2b(v1.x), (short)f2b(v1.y), (short)f2b(v1.z), (short)f2b(v1.w) };
  ((bf16x8*)out)[i] = o;
}

__global__ void k_build_wt(const float* __restrict__ Wl, const float* __restrict__ Wr,
                           const float* __restrict__ skW, const float* __restrict__ pjW,
                           unsigned short* __restrict__ wt){
  int idx = blockIdx.x * 256 + threadIdx.x;
  if(idx >= 19 * 16384) return;
  int mat = idx >> 14, r = idx & 16383;
  int n = r >> 7, k = r & 127;
  const float* src;
  if(mat < 8)       src = Wl + mat * 16384;
  else if(mat < 16) src = Wr + (mat - 8) * 16384;
  else if(mat < 18) src = skW + (mat - 16) * 16384;
  else              src = pjW;
  wt[idx] = f2b(src[k * 128 + n]);
}

// ---------------- counting sort by key = dst*4 + ea ----------------
__global__ void k_hist_key(const int* __restrict__ dst, const int* __restrict__ ea,
                           unsigned int* __restrict__ cnt, int E){
  int i = blockIdx.x * 256 + threadIdx.x;
  if(i < E) atomicAdd(cnt + (dst[i]*4 + ea[i]), 1u);
}

__device__ __forceinline__ unsigned wave_iscan(unsigned v, int lane){
  #pragma unroll
  for(int ofs = 1; ofs < 64; ofs <<= 1){
    unsigned y = __shfl_up(v, ofs);
    if(lane >= ofs) v += y;
  }
  return v;  // inclusive scan across 64 lanes
}

// hierarchical exclusive scan: stage 1 — 4096 bins/block
__global__ __launch_bounds__(256) void k_scan_partial(
    const unsigned int* __restrict__ cnt, unsigned int* __restrict__ off,
    unsigned int* __restrict__ bsum, int n){
  __shared__ unsigned int buf[4096];
  __shared__ unsigned int wofs[4];
  const int base = blockIdx.x * 4096;
  for(int i = threadIdx.x; i < 4096; i += 256){
    int idx = base + i;
    buf[i] = (idx < n) ? cnt[idx] : 0u;
  }
  __syncthreads();
  const int lane = threadIdx.x & 63, wid = threadIdx.x >> 6;
  const int b = threadIdx.x * 16;
  unsigned loc[16]; unsigned s = 0;
  #pragma unroll
  for(int i = 0; i < 16; ++i){ loc[i] = s; s += buf[b + i]; }
  unsigned isc = wave_iscan(s, lane);
  unsigned texc = isc - s;              // exclusive within wave
  if(lane == 63) wofs[wid] = isc;       // wave total
  __syncthreads();
  unsigned wbase = 0;
  for(int w = 0; w < wid; ++w) wbase += wofs[w];
  unsigned tbase = wbase + texc;
  #pragma unroll
  for(int i = 0; i < 16; ++i){
    int idx = base + b + i;
    if(idx < n) off[idx] = tbase + loc[i];
  }
  if(threadIdx.x == 255) bsum[blockIdx.x] = wbase + isc;  // block total
}

// stage 2 — scan block totals (nblk <= 64), write grand total to off[n]
__global__ void k_scan_bsum(unsigned int* __restrict__ bsum, unsigned int* __restrict__ off,
                            int nblk, int n){
  if(threadIdx.x == 0 && blockIdx.x == 0){
    unsigned acc = 0;
    for(int i = 0; i < nblk; ++i){ unsigned v = bsum[i]; bsum[i] = acc; acc += v; }
    off[n] = acc;
  }
}

// stage 3 — add block base; also produce cursor copy for scatter
__global__ void k_scan_add(unsigned int* __restrict__ off, unsigned int* __restrict__ cur,
                           const unsigned int* __restrict__ bsum, int n){
  int i = blockIdx.x * 256 + threadIdx.x;
  if(i < n){
    unsigned v = off[i] + bsum[i >> 12];
    off[i] = v;
    cur[i] = v;
  }
}

__global__ void k_scatter_key(const int* __restrict__ dst, const int* __restrict__ ea,
                              const int* __restrict__ src,
                              unsigned int* __restrict__ cursor,
                              int* __restrict__ psrc, int E){
  int i = blockIdx.x * 256 + threadIdx.x;
  if(i < E){
    unsigned int pos = atomicAdd(cursor + (dst[i]*4 + ea[i]), 1u);
    psrc[pos] = src[i];
  }
}

// ---------------- GEMM (Wt staged in LDS, padded stride 136) ----------------
template<bool OUT_BF16>
__global__ __launch_bounds__(256) void k_gemm(
    const unsigned short* __restrict__ A, int M,
    const unsigned short* __restrict__ wtBase, long wtStride,
    const float* __restrict__ biasBase, int biasStride,
    void* __restrict__ outBase, long outStride)
{
  __shared__ unsigned short lw[128 * 136];
  const unsigned short* Wt = wtBase + (long)blockIdx.y * wtStride;
  #pragma unroll
  for(int it = 0; it < 8; ++it){
    int idx = it * 256 + threadIdx.x;     // 0..2047
    int row = idx >> 4, c8 = idx & 15;
    bf16x8 v = *(const bf16x8*)(Wt + row * 128 + c8 * 8);
    *(bf16x8*)(lw + row * 136 + c8 * 8) = v;
  }

  const float* bias = biasBase + (long)blockIdx.y * biasStride;
  const int wave = threadIdx.x >> 6, lane = threadIdx.x & 63;
  const int l16 = lane & 15, lhi = lane >> 4;

  const int row0 = blockIdx.x * 64 + wave * 16;
  const int arow = row0 + l16;
  const bf16x8 zf = {0,0,0,0,0,0,0,0};
  bf16x8 afr[4];
  if(arow < M){
    #pragma unroll
    for(int kb = 0; kb < 4; ++kb)
      afr[kb] = *(const bf16x8*)(A + (long)arow*128 + kb*32 + lhi*8);
  } else {
    #pragma unroll
    for(int kb = 0; kb < 4; ++kb) afr[kb] = zf;
  }
  __syncthreads();

  const f32x4 z4 = {0.f,0.f,0.f,0.f};
  f32x4 acc[8];
  #pragma unroll
  for(int cb = 0; cb < 8; ++cb) acc[cb] = z4;
  #pragma unroll
  for(int cb = 0; cb < 8; ++cb){
    #pragma unroll
    for(int kb = 0; kb < 4; ++kb){
      bf16x8 bfr = *(const bf16x8*)(lw + (cb*16 + l16)*136 + kb*32 + lhi*8);
      acc[cb] = __builtin_amdgcn_mfma_f32_16x16x32_bf16(afr[kb], bfr, acc[cb], 0, 0, 0);
    }
  }

  #pragma unroll
  for(int cb = 0; cb < 8; ++cb){
    int col = cb*16 + l16;
    float bv = bias[col];
    #pragma unroll
    for(int q = 0; q < 4; ++q){
      int rrow = row0 + lhi*4 + q;
      if(rrow < M){
        float v = acc[cb][q] + bv;
        long oidx = (long)blockIdx.y * outStride + (long)rrow * 128 + col;
        if(OUT_BF16) ((unsigned short*)outBase)[oidx] = f2b(v);
        else         ((float*)outBase)[oidx] = v;
      }
    }
  }
}

// ---------------- per-dst fused attention+aggregate+BN ----------------
// Block = 256 threads = 4 waves; wave r handles relation r of dst t = blockIdx.x.
// Per-wave: online softmax with defer-max (THR=8) over segment [off[t*4+r], off[t*4+r+1]).
// Per-r BN contributions combined via LDS, wave 0 does the final out += sum.
__global__ __launch_bounds__(256) void k_dst_agg(
    const unsigned int* __restrict__ off, const int* __restrict__ psrc,
    const unsigned short* __restrict__ xl, const unsigned short* __restrict__ xr,
    const float* __restrict__ att,
    const float* __restrict__ conv_b, const float* __restrict__ bn_g, const float* __restrict__ bn_b,
    const float* __restrict__ bn_m, const float* __restrict__ bn_v,
    float* __restrict__ out, int N, int nt)
{
  __shared__ float contrib[4][128];
  const int t = blockIdx.x;
  const int r = threadIdx.x >> 6;        // wave id == relation (wave-uniform)
  const int lane = threadIdx.x & 63;
  const int sub  = lane >> 4;
  const int l16  = lane & 15;

  const bf16x8 xrv = *(const bf16x8*)(xr + ((long)r*nt + t)*128 + l16*8);
  float xrf[8];
  #pragma unroll
  for(int q = 0; q < 8; ++q) xrf[q] = b2f((unsigned short)xrv[q]);
  const float4 a0 = ((const float4*)(att + r*128 + l16*8))[0];
  const float4 a1 = ((const float4*)(att + r*128 + l16*8))[1];
  const float av[8] = {a0.x,a0.y,a0.z,a0.w,a1.x,a1.y,a1.z,a1.w};

  const unsigned s0 = off[t*4 + r], s1 = off[t*4 + r + 1];

  float m = -3.0e38f, den = 0.f;
  float acc[8];
  #pragma unroll
  for(int q = 0; q < 8; ++q) acc[q] = 0.f;

  for(unsigned e = s0 + sub; e < s1; e += 4){
    int s = psrc[e];
    bf16x8 xlv = *(const bf16x8*)(xl + ((long)r*N + s)*128 + l16*8);
    float xlf[8];
    #pragma unroll
    for(int q = 0; q < 8; ++q) xlf[q] = b2f((unsigned short)xlv[q]);
    float part = 0.f;
    #pragma unroll
    for(int q = 0; q < 8; ++q){
      float v = xlf[q] + xrf[q];
      v = v >= 0.f ? v : cSLOPE * v;
      part += v * av[q];
    }
    part += __shfl_xor(part, 1);
    part += __shfl_xor(part, 2);         // quad now holds head logit
    float p;
    if(part > m + 8.f){                  // defer-max: rescale only on big jumps
      float corr = __expf(m - part);     // exp(-inf)=0 on first edge
      den *= corr;
      #pragma unroll
      for(int q = 0; q < 8; ++q) acc[q] *= corr;
      m = part;
      p = 1.f;
    } else {
      p = __expf(part - m);              // bounded by e^8
    }
    den += p;
    #pragma unroll
    for(int q = 0; q < 8; ++q) acc[q] += p * xlf[q];
  }

  // merge the 4 edge-slots (lanes differing in bits 4,5) — exact log-sum-exp
  #pragma unroll
  for(int ofs = 16; ofs <= 32; ofs <<= 1){
    float m2 = __shfl_xor(m, ofs);
    float d2 = __shfl_xor(den, ofs);
    float M = fmaxf(m, m2);
    float sA = __expf(m - M), sB = __expf(m2 - M);
    den = den * sA + d2 * sB;
    #pragma unroll
    for(int q = 0; q < 8; ++q){
      float a2 = __shfl_xor(acc[q], ofs);
      acc[q] = acc[q] * sA + a2 * sB;
    }
    m = M;
  }

  if(sub == 0){
    const float inv = 1.f / fmaxf(den, 1e-16f);
    #pragma unroll
    for(int q = 0; q < 8; ++q){
      int c = l16*8 + q;
      float cb = conv_b[r*128 + c], gg = bn_g[r*128 + c], bb = bn_b[r*128 + c];
      float mm = bn_m[r*128 + c],  vv = bn_v[r*128 + c];
      contrib[r][c] = (acc[q] * inv + cb - mm) * rsqrtf(vv + cEPS) * gg + bb;
    }
  }
  __syncthreads();
  if(threadIdx.x < 64){
    int c = threadIdx.x * 2;
    float2 o = *(float2*)(out + (long)t*128 + c);
    o.x += contrib[0][c]   + contrib[1][c]   + contrib[2][c]   + contrib[3][c];
    o.y += contrib[0][c+1] + contrib[1][c+1] + contrib[2][c+1] + contrib[3][c+1];
    *(float2*)(out + (long)t*128 + c) = o;
  }
}

// ---------------- ELU ----------------
__global__ void k_elu_act(const float* __restrict__ in, unsigned short* __restrict__ outBf,
                          float* __restrict__ outF32, int n4){
  int i = blockIdx.x * 256 + threadIdx.x;
  if(i >= n4) return;
  float4 v = ((const float4*)in)[i];
  float4 e;
  e.x = v.x > 0.f ? v.x : __expf(v.x) - 1.f;
  e.y = v.y > 0.f ? v.y : __expf(v.y) - 1.f;
  e.z = v.z > 0.f ? v.z : __expf(v.z) - 1.f;
  e.w = v.w > 0.f ? v.w : __expf(v.w) - 1.f;
  ushort4 o = { f2b(e.x), f2b(e.y), f2b(e.z), f2b(e.w) };
  ((ushort4*)outBf)[i] = o;
  if(outF32) ((float4*)outF32)[i] = e;
}

// ---------------- projection BN + PReLU ----------------
__global__ void k_pbn_prelu(float* __restrict__ hbuf, const float* __restrict__ g, const float* __restrict__ b,
                            const float* __restrict__ m, const float* __restrict__ v,
                            const float* __restrict__ a, int n4){
  int i = blockIdx.x * 256 + threadIdx.x;
  if(i >= n4) return;
  int c4 = i & 31;
  float4 x  = ((const float4*)hbuf)[i];
  float4 gg = ((const float4*)g)[c4], bb = ((const float4*)b)[c4];
  float4 mm = ((const float4*)m)[c4], vv = ((const float4*)v)[c4];
  float al = a[0];
  float4 y;
  y.x = (x.x - mm.x) * rsqrtf(vv.x + cEPS) * gg.x + bb.x; y.x = y.x > 0.f ? y.x : al * y.x;
  y.y = (x.y - mm.y) * rsqrtf(vv.y + cEPS) * gg.y + bb.y; y.y = y.y > 0.f ? y.y : al * y.y;
  y.z = (x.z - mm.z) * rsqrtf(vv.z + cEPS) * gg.z + bb.z; y.z = y.z > 0.f ? y.z : al * y.z;
  y.w = (x.w - mm.w) * rsqrtf(vv.w + cEPS) * gg.w + bb.w; y.w = y.w > 0.f ? y.w : al * y.w;
  ((float4*)hbuf)[i] = y;
}

extern "C" void kernel_launch(void* const* d_in, const int* in_sizes, int n_in,
                              void* d_out, int out_size, void* d_ws, size_t ws_size,
                              hipStream_t stream)
{
  const float* x0     = (const float*)d_in[0];
  const int*   src0   = (const int*)d_in[1];
  const int*   dst0   = (const int*)d_in[2];
  const int*   ea0    = (const int*)d_in[3];
  const int*   src1   = (const int*)d_in[4];
  const int*   dst1   = (const int*)d_in[5];
  const int*   ea1    = (const int*)d_in[6];
  const float* Wl     = (const float*)d_in[7];
  const float* Wr     = (const float*)d_in[8];
  const float* bl     = (const float*)d_in[9];
  const float* br     = (const float*)d_in[10];
  const float* att    = (const float*)d_in[11];
  const float* conv_b = (const float*)d_in[12];
  const float* bn_g   = (const float*)d_in[13];
  const float* bn_b   = (const float*)d_in[14];
  const float* bn_m   = (const float*)d_in[15];
  const float* bn_v   = (const float*)d_in[16];
  const float* skip_W = (const float*)d_in[17];
  const float* skip_b = (const float*)d_in[18];
  const float* proj_W = (const float*)d_in[19];
  const float* proj_b = (const float*)d_in[20];
  const float* pbn_g  = (const float*)d_in[21];
  const float* pbn_b  = (const float*)d_in[22];
  const float* pbn_m  = (const float*)d_in[23];
  const float* pbn_v  = (const float*)d_in[24];
  const float* prelu_a= (const float*)d_in[25];

  const int N0 = in_sizes[0] / 128;
  const int E0 = in_sizes[1];
  const int E1 = in_sizes[4];
  const int N1 = 30000;
  const int N2 = 8000;
  const int jc = 4;

  auto al = [](size_t x){ return (x + 255) & ~(size_t)255; };
  char* p = (char*)d_ws;
  auto carve = [&](size_t bytes){ char* r = p; p += al(bytes); return r; };
  unsigned short* wt    = (unsigned short*)carve((size_t)19*16384*2);
  unsigned short* xbf   = (unsigned short*)carve((size_t)N0*256);
  unsigned short* xlb   = (unsigned short*)carve((size_t)jc*N0*256);
  unsigned short* xrb   = (unsigned short*)carve((size_t)jc*N1*256);
  unsigned int*   cnt   = (unsigned int*)carve((size_t)(N1*4+1)*4);
  unsigned int*   off   = (unsigned int*)carve((size_t)(N1*4+1)*4);
  unsigned int*   cur   = (unsigned int*)carve((size_t)(N1*4+1)*4);
  unsigned int*   bsum  = (unsigned int*)carve((size_t)256*4);
  int*            psrc  = (int*)carve((size_t)E0*4);
  float*          out1  = (float*)carve((size_t)N1*512);

  k_f32_to_bf16<<<(N0*16 + 255)/256, 256, 0, stream>>>(x0, xbf, N0*16);
  k_build_wt<<<(19*16384 + 255)/256, 256, 0, stream>>>(Wl, Wr, skip_W, proj_W, wt);

  auto run_layer = [&](int li, int N, int nt, const int* src, const int* dst, const int* ea, int E){
    const int nbins = nt * 4;
    const int nblk = (nbins + 4095) / 4096;
    hipMemsetAsync(cnt, 0, (size_t)(nbins + 1) * 4, stream);
    k_hist_key<<<(E + 255)/256, 256, 0, stream>>>(dst, ea, cnt, E);
    k_scan_partial<<<nblk, 256, 0, stream>>>(cnt, off, bsum, nbins);
    k_scan_bsum<<<1, 64, 0, stream>>>(bsum, off, nblk, nbins);
    k_scan_add<<<(nbins + 255)/256, 256, 0, stream>>>(off, cur, bsum, nbins);
    k_scatter_key<<<(E + 255)/256, 256, 0, stream>>>(dst, ea, src, cur, psrc, E);

    k_gemm<false><<<dim3((nt+63)/64, 1), 256, 0, stream>>>(
        xbf, nt, wt + (16+li)*16384, 0, skip_b + li*128, 0, out1, 0);
    k_gemm<true><<<dim3((N+63)/64, jc), 256, 0, stream>>>(
        xbf, N,  wt + (li*4)*16384,   16384, bl + (li*4)*128, 128, xlb, (long)N*128);
    k_gemm<true><<<dim3((nt+63)/64, jc), 256, 0, stream>>>(
        xbf, nt, wt + (8+li*4)*16384, 16384, br + (li*4)*128, 128, xrb, (long)nt*128);
    k_dst_agg<<<nt, 256, 0, stream>>>(
        off, psrc, xlb, xrb, att + li*512,
        conv_b + li*512, bn_g + li*512, bn_b + li*512, bn_m + li*512, bn_v + li*512,
        out1, N, nt);
  };

  run_layer(0, N0, N1, src0, dst0, ea0, E0);
  k_elu_act<<<(N1*32 + 255)/256, 256, 0, stream>>>(out1, xbf, nullptr, N1*32);
  run_layer(1, N1, N2, src1, dst1, ea1, E1);

  float* outX = (float*)d_out;
  float* outP = (float*)d_out + (size_t)N2*128;
  k_elu_act<<<(N2*32 + 255)/256, 256, 0, stream>>>(out1, xbf, outX, N2*32);
  k_gemm<false><<<dim3((N2+63)/64, 1), 256, 0, stream>>>(
      xbf, N2, wt + 18*16384, 0, proj_b, 0, outP, 0);
  k_pbn_prelu<<<(N2*32 + 255)/256, 256, 0, stream>>>(outP, pbn_g, pbn_b, pbn_m, pbn_v, prelu_a, N2*32);
}

// Round 12
// 448.246 us; speedup vs baseline: 2.8351x; 1.0663x over previous
//
#include <hip/hip_runtime.h>
#include <stdint.h>

typedef short bf16x8 __attribute__((ext_vector_type(8)));
typedef float f32x4 __attribute__((ext_vector_type(4)));

constexpr float cEPS = 1e-5f;
constexpr float cSLOPE = 0.2f;

__device__ __forceinline__ unsigned short f2b(float f){
  unsigned u = __float_as_uint(f);
  u = (u + 0x7fffu + ((u >> 16) & 1u)) >> 16;
  return (unsigned short)u;
}
__device__ __forceinline__ float b2f(unsigned short b){
  return __uint_as_float(((unsigned)b) << 16);
}

// ---------------- preprocessing ----------------
__global__ void k_f32_to_bf16(const float* __restrict__ in, unsigned short* __restrict__ out, int n8){
  int i = blockIdx.x * 256 + threadIdx.x;
  if(i >= n8) return;
  float4 v0 = ((const float4*)in)[i*2];
  float4 v1 = ((const float4*)in)[i*2 + 1];
  bf16x8 o = { (short)f2b(v0.x), (short)f2b(v0.y), (short)f2b(v0.z), (short)f2b(v0.w),
               (short)f2b(v1.x), (short)f2b(v1.y), (short)f2b(v1.z), (short)f2b(v1.w) };
  ((bf16x8*)out)[i] = o;
}

__global__ void k_build_wt(const float* __restrict__ Wl, const float* __restrict__ Wr,
                           const float* __restrict__ skW, const float* __restrict__ pjW,
                           unsigned short* __restrict__ wt){
  int idx = blockIdx.x * 256 + threadIdx.x;
  if(idx >= 19 * 16384) return;
  int mat = idx >> 14, r = idx & 16383;
  int n = r >> 7, k = r & 127;
  const float* src;
  if(mat < 8)       src = Wl + mat * 16384;
  else if(mat < 16) src = Wr + (mat - 8) * 16384;
  else if(mat < 18) src = skW + (mat - 16) * 16384;
  else              src = pjW;
  wt[idx] = f2b(src[k * 128 + n]);
}

// ---------------- counting sort by key = dst*4 + ea ----------------
__global__ void k_hist_key(const int* __restrict__ dst, const int* __restrict__ ea,
                           unsigned int* __restrict__ cnt, int E){
  int i = blockIdx.x * 256 + threadIdx.x;
  if(i < E) atomicAdd(cnt + (dst[i]*4 + ea[i]), 1u);
}

__device__ __forceinline__ unsigned wave_iscan(unsigned v, int lane){
  #pragma unroll
  for(int ofs = 1; ofs < 64; ofs <<= 1){
    unsigned y = __shfl_up(v, ofs);
    if(lane >= ofs) v += y;
  }
  return v;
}

// stage 1 — 4096 bins/block; bsum gets RAW block totals
__global__ __launch_bounds__(256) void k_scan_partial(
    const unsigned int* __restrict__ cnt, unsigned int* __restrict__ off,
    unsigned int* __restrict__ bsum, int n){
  __shared__ unsigned int buf[4096];
  __shared__ unsigned int wofs[4];
  const int base = blockIdx.x * 4096;
  for(int i = threadIdx.x; i < 4096; i += 256){
    int idx = base + i;
    buf[i] = (idx < n) ? cnt[idx] : 0u;
  }
  __syncthreads();
  const int lane = threadIdx.x & 63, wid = threadIdx.x >> 6;
  const int b = threadIdx.x * 16;
  unsigned loc[16]; unsigned s = 0;
  #pragma unroll
  for(int i = 0; i < 16; ++i){ loc[i] = s; s += buf[b + i]; }
  unsigned isc = wave_iscan(s, lane);
  unsigned texc = isc - s;
  if(lane == 63) wofs[wid] = isc;
  __syncthreads();
  unsigned wbase = 0;
  for(int w = 0; w < wid; ++w) wbase += wofs[w];
  unsigned tbase = wbase + texc;
  #pragma unroll
  for(int i = 0; i < 16; ++i){
    int idx = base + b + i;
    if(idx < n) off[idx] = tbase + loc[i];
  }
  if(threadIdx.x == 255) bsum[blockIdx.x] = wbase + isc;
}

// stage 2 — add block base (computed by summing raw bsum); write cursor + grand total
__global__ void k_scan_add(unsigned int* __restrict__ off, unsigned int* __restrict__ cur,
                           const unsigned int* __restrict__ bsum, const unsigned int* __restrict__ cnt,
                           int n){
  int i = blockIdx.x * 256 + threadIdx.x;
  if(i >= n) return;
  int myblk = i >> 12;
  unsigned base = 0;
  for(int j = 0; j < myblk; ++j) base += bsum[j];   // wave-uniform, L2-hit, <=29 iters
  unsigned v = off[i] + base;
  off[i] = v;
  cur[i] = v;
  if(i == n - 1) off[n] = v + cnt[i];
}

__global__ void k_scatter_key(const int* __restrict__ dst, const int* __restrict__ ea,
                              const int* __restrict__ src,
                              unsigned int* __restrict__ cursor,
                              int* __restrict__ psrc, int E){
  int i = blockIdx.x * 256 + threadIdx.x;
  if(i < E){
    unsigned int pos = atomicAdd(cursor + (dst[i]*4 + ea[i]), 1u);
    psrc[pos] = src[i];
  }
}

// ---------------- fused per-layer GEMM: blockIdx.y 0-3 xl, 4-7 xr, 8 skip ----------------
// Wt staged in LDS (stride 136 pad). out bf16 (xl/xr) or f32 (skip).
__global__ __launch_bounds__(256) void k_gemm_layer(
    const unsigned short* __restrict__ A,
    const unsigned short* __restrict__ wt,
    const float* __restrict__ bl, const float* __restrict__ br, const float* __restrict__ skip_b,
    unsigned short* __restrict__ xlb, unsigned short* __restrict__ xrb, float* __restrict__ out1,
    int li, int N, int nt)
{
  const int y = blockIdx.y;
  int M; const unsigned short* Wt; const float* bias;
  unsigned short* outB = nullptr; float* outF = nullptr;
  if(y < 4){
    M = N;  Wt = wt + (li*4 + y)*16384;      bias = bl + (li*4 + y)*128;
    outB = xlb + (long)y*N*128;
  } else if(y < 8){
    int r = y - 4;
    M = nt; Wt = wt + (8 + li*4 + r)*16384;  bias = br + (li*4 + r)*128;
    outB = xrb + (long)r*nt*128;
  } else {
    M = nt; Wt = wt + (16 + li)*16384;       bias = skip_b + li*128;
    outF = out1;
  }
  if(blockIdx.x * 64 >= M) return;

  __shared__ unsigned short lw[128 * 136];
  #pragma unroll
  for(int it = 0; it < 8; ++it){
    int idx = it * 256 + threadIdx.x;
    int row = idx >> 4, c8 = idx & 15;
    bf16x8 v = *(const bf16x8*)(Wt + row * 128 + c8 * 8);
    *(bf16x8*)(lw + row * 136 + c8 * 8) = v;
  }

  const int wave = threadIdx.x >> 6, lane = threadIdx.x & 63;
  const int l16 = lane & 15, lhi = lane >> 4;
  const int row0 = blockIdx.x * 64 + wave * 16;
  const int arow = row0 + l16;
  const bf16x8 zf = {0,0,0,0,0,0,0,0};
  bf16x8 afr[4];
  if(arow < M){
    #pragma unroll
    for(int kb = 0; kb < 4; ++kb)
      afr[kb] = *(const bf16x8*)(A + (long)arow*128 + kb*32 + lhi*8);
  } else {
    #pragma unroll
    for(int kb = 0; kb < 4; ++kb) afr[kb] = zf;
  }
  __syncthreads();

  const f32x4 z4 = {0.f,0.f,0.f,0.f};
  f32x4 acc[8];
  #pragma unroll
  for(int cb = 0; cb < 8; ++cb) acc[cb] = z4;
  #pragma unroll
  for(int cb = 0; cb < 8; ++cb){
    #pragma unroll
    for(int kb = 0; kb < 4; ++kb){
      bf16x8 bfr = *(const bf16x8*)(lw + (cb*16 + l16)*136 + kb*32 + lhi*8);
      acc[cb] = __builtin_amdgcn_mfma_f32_16x16x32_bf16(afr[kb], bfr, acc[cb], 0, 0, 0);
    }
  }

  #pragma unroll
  for(int cb = 0; cb < 8; ++cb){
    int col = cb*16 + l16;
    float bv = bias[col];
    #pragma unroll
    for(int q = 0; q < 4; ++q){
      int rrow = row0 + lhi*4 + q;
      if(rrow < M){
        float v = acc[cb][q] + bv;
        long oidx = (long)rrow * 128 + col;
        if(outB) outB[oidx] = f2b(v);
        else     outF[oidx] = v;
      }
    }
  }
}

// ---------------- proj GEMM with fused BN + PReLU ----------------
__global__ __launch_bounds__(256) void k_gemm_proj(
    const unsigned short* __restrict__ A, int M,
    const unsigned short* __restrict__ Wt, const float* __restrict__ bias,
    const float* __restrict__ pg, const float* __restrict__ pb,
    const float* __restrict__ pm, const float* __restrict__ pv,
    const float* __restrict__ pa, float* __restrict__ outP)
{
  __shared__ unsigned short lw[128 * 136];
  #pragma unroll
  for(int it = 0; it < 8; ++it){
    int idx = it * 256 + threadIdx.x;
    int row = idx >> 4, c8 = idx & 15;
    bf16x8 v = *(const bf16x8*)(Wt + row * 128 + c8 * 8);
    *(bf16x8*)(lw + row * 136 + c8 * 8) = v;
  }
  const int wave = threadIdx.x >> 6, lane = threadIdx.x & 63;
  const int l16 = lane & 15, lhi = lane >> 4;
  const int row0 = blockIdx.x * 64 + wave * 16;
  const int arow = row0 + l16;
  const bf16x8 zf = {0,0,0,0,0,0,0,0};
  bf16x8 afr[4];
  if(arow < M){
    #pragma unroll
    for(int kb = 0; kb < 4; ++kb)
      afr[kb] = *(const bf16x8*)(A + (long)arow*128 + kb*32 + lhi*8);
  } else {
    #pragma unroll
    for(int kb = 0; kb < 4; ++kb) afr[kb] = zf;
  }
  __syncthreads();

  const f32x4 z4 = {0.f,0.f,0.f,0.f};
  f32x4 acc[8];
  #pragma unroll
  for(int cb = 0; cb < 8; ++cb) acc[cb] = z4;
  #pragma unroll
  for(int cb = 0; cb < 8; ++cb){
    #pragma unroll
    for(int kb = 0; kb < 4; ++kb){
      bf16x8 bfr = *(const bf16x8*)(lw + (cb*16 + l16)*136 + kb*32 + lhi*8);
      acc[cb] = __builtin_amdgcn_mfma_f32_16x16x32_bf16(afr[kb], bfr, acc[cb], 0, 0, 0);
    }
  }
  const float a0 = pa[0];
  #pragma unroll
  for(int cb = 0; cb < 8; ++cb){
    int col = cb*16 + l16;
    float bv = bias[col];
    float gg = pg[col], bb = pb[col], mm = pm[col], vv = pv[col];
    float rs = rsqrtf(vv + cEPS);
    #pragma unroll
    for(int q = 0; q < 4; ++q){
      int rrow = row0 + lhi*4 + q;
      if(rrow < M){
        float h = (acc[cb][q] + bv - mm) * rs * gg + bb;
        h = h > 0.f ? h : a0 * h;
        outP[(long)rrow * 128 + col] = h;
      }
    }
  }
}

// ---------------- per-dst fused attention+aggregate+BN+skip+ELU ----------------
// Block = 4 waves; wave r handles relation r of dst t. Defer-max online softmax.
// Epilogue: out = elu(skipIn[t] + sum_r BN_r(...)) -> bf16 outBf (and optional f32 outF32).
__global__ __launch_bounds__(256) void k_dst_agg(
    const unsigned int* __restrict__ off, const int* __restrict__ psrc,
    const unsigned short* __restrict__ xl, const unsigned short* __restrict__ xr,
    const float* __restrict__ att,
    const float* __restrict__ conv_b, const float* __restrict__ bn_g, const float* __restrict__ bn_b,
    const float* __restrict__ bn_m, const float* __restrict__ bn_v,
    const float* __restrict__ skipIn, unsigned short* __restrict__ outBf,
    float* __restrict__ outF32, int N, int nt)
{
  __shared__ float contrib[4][128];
  const int t = blockIdx.x;
  const int r = threadIdx.x >> 6;
  const int lane = threadIdx.x & 63;
  const int sub  = lane >> 4;
  const int l16  = lane & 15;

  const bf16x8 xrv = *(const bf16x8*)(xr + ((long)r*nt + t)*128 + l16*8);
  float xrf[8];
  #pragma unroll
  for(int q = 0; q < 8; ++q) xrf[q] = b2f((unsigned short)xrv[q]);
  const float4 a0 = ((const float4*)(att + r*128 + l16*8))[0];
  const float4 a1 = ((const float4*)(att + r*128 + l16*8))[1];
  const float av[8] = {a0.x,a0.y,a0.z,a0.w,a1.x,a1.y,a1.z,a1.w};

  const unsigned s0 = off[t*4 + r], s1 = off[t*4 + r + 1];

  float m = -3.0e38f, den = 0.f;
  float acc[8];
  #pragma unroll
  for(int q = 0; q < 8; ++q) acc[q] = 0.f;

  for(unsigned e = s0 + sub; e < s1; e += 4){
    int s = psrc[e];
    bf16x8 xlv = *(const bf16x8*)(xl + ((long)r*N + s)*128 + l16*8);
    float xlf[8];
    #pragma unroll
    for(int q = 0; q < 8; ++q) xlf[q] = b2f((unsigned short)xlv[q]);
    float part = 0.f;
    #pragma unroll
    for(int q = 0; q < 8; ++q){
      float v = xlf[q] + xrf[q];
      v = v >= 0.f ? v : cSLOPE * v;
      part += v * av[q];
    }
    part += __shfl_xor(part, 1);
    part += __shfl_xor(part, 2);
    float p;
    if(part > m + 8.f){
      float corr = __expf(m - part);
      den *= corr;
      #pragma unroll
      for(int q = 0; q < 8; ++q) acc[q] *= corr;
      m = part;
      p = 1.f;
    } else {
      p = __expf(part - m);
    }
    den += p;
    #pragma unroll
    for(int q = 0; q < 8; ++q) acc[q] += p * xlf[q];
  }

  #pragma unroll
  for(int ofs = 16; ofs <= 32; ofs <<= 1){
    float m2 = __shfl_xor(m, ofs);
    float d2 = __shfl_xor(den, ofs);
    float M = fmaxf(m, m2);
    float sA = __expf(m - M), sB = __expf(m2 - M);
    den = den * sA + d2 * sB;
    #pragma unroll
    for(int q = 0; q < 8; ++q){
      float a2 = __shfl_xor(acc[q], ofs);
      acc[q] = acc[q] * sA + a2 * sB;
    }
    m = M;
  }

  if(sub == 0){
    const float inv = 1.f / fmaxf(den, 1e-16f);
    #pragma unroll
    for(int q = 0; q < 8; ++q){
      int c = l16*8 + q;
      float cb = conv_b[r*128 + c], gg = bn_g[r*128 + c], bb = bn_b[r*128 + c];
      float mm = bn_m[r*128 + c],  vv = bn_v[r*128 + c];
      contrib[r][c] = (acc[q] * inv + cb - mm) * rsqrtf(vv + cEPS) * gg + bb;
    }
  }
  __syncthreads();
  if(threadIdx.x < 64){
    int c = threadIdx.x * 2;
    float2 o = *(const float2*)(skipIn + (long)t*128 + c);
    float ox = o.x + contrib[0][c]   + contrib[1][c]   + contrib[2][c]   + contrib[3][c];
    float oy = o.y + contrib[0][c+1] + contrib[1][c+1] + contrib[2][c+1] + contrib[3][c+1];
    ox = ox > 0.f ? ox : __expf(ox) - 1.f;
    oy = oy > 0.f ? oy : __expf(oy) - 1.f;
    ushort2 ob = { f2b(ox), f2b(oy) };
    *(ushort2*)(outBf + (long)t*128 + c) = ob;
    if(outF32){
      float2 of = { ox, oy };
      *(float2*)(outF32 + (long)t*128 + c) = of;
    }
  }
}

extern "C" void kernel_launch(void* const* d_in, const int* in_sizes, int n_in,
                              void* d_out, int out_size, void* d_ws, size_t ws_size,
                              hipStream_t stream)
{
  const float* x0     = (const float*)d_in[0];
  const int*   src0   = (const int*)d_in[1];
  const int*   dst0   = (const int*)d_in[2];
  const int*   ea0    = (const int*)d_in[3];
  const int*   src1   = (const int*)d_in[4];
  const int*   dst1   = (const int*)d_in[5];
  const int*   ea1    = (const int*)d_in[6];
  const float* Wl     = (const float*)d_in[7];
  const float* Wr     = (const float*)d_in[8];
  const float* bl     = (const float*)d_in[9];
  const float* br     = (const float*)d_in[10];
  const float* att    = (const float*)d_in[11];
  const float* conv_b = (const float*)d_in[12];
  const float* bn_g   = (const float*)d_in[13];
  const float* bn_b   = (const float*)d_in[14];
  const float* bn_m   = (const float*)d_in[15];
  const float* bn_v   = (const float*)d_in[16];
  const float* skip_W = (const float*)d_in[17];
  const float* skip_b = (const float*)d_in[18];
  const float* proj_W = (const float*)d_in[19];
  const float* proj_b = (const float*)d_in[20];
  const float* pbn_g  = (const float*)d_in[21];
  const float* pbn_b  = (const float*)d_in[22];
  const float* pbn_m  = (const float*)d_in[23];
  const float* pbn_v  = (const float*)d_in[24];
  const float* prelu_a= (const float*)d_in[25];

  const int N0 = in_sizes[0] / 128;
  const int E0 = in_sizes[1];
  const int E1 = in_sizes[4];
  const int N1 = 30000;
  const int N2 = 8000;
  const int jc = 4;

  auto al = [](size_t x){ return (x + 255) & ~(size_t)255; };
  char* p = (char*)d_ws;
  auto carve = [&](size_t bytes){ char* r = p; p += al(bytes); return r; };
  unsigned short* wt    = (unsigned short*)carve((size_t)19*16384*2);
  unsigned short* xbf   = (unsigned short*)carve((size_t)N0*256);
  unsigned short* xlb   = (unsigned short*)carve((size_t)jc*N0*256);
  unsigned short* xrb   = (unsigned short*)carve((size_t)jc*N1*256);
  unsigned int*   cnt   = (unsigned int*)carve((size_t)(N1*4+1)*4);
  unsigned int*   off   = (unsigned int*)carve((size_t)(N1*4+1)*4);
  unsigned int*   cur   = (unsigned int*)carve((size_t)(N1*4+1)*4);
  unsigned int*   bsum  = (unsigned int*)carve((size_t)256*4);
  int*            psrc  = (int*)carve((size_t)E0*4);
  float*          out1  = (float*)carve((size_t)N1*512);

  k_f32_to_bf16<<<(N0*16 + 255)/256, 256, 0, stream>>>(x0, xbf, N0*16);
  k_build_wt<<<(19*16384 + 255)/256, 256, 0, stream>>>(Wl, Wr, skip_W, proj_W, wt);

  auto run_layer = [&](int li, int N, int nt, const int* src, const int* dst, const int* ea, int E,
                       unsigned short* outBf, float* outF32){
    const int nbins = nt * 4;
    const int nblk = (nbins + 4095) / 4096;
    hipMemsetAsync(cnt, 0, (size_t)(nbins + 1) * 4, stream);
    k_hist_key<<<(E + 255)/256, 256, 0, stream>>>(dst, ea, cnt, E);
    k_scan_partial<<<nblk, 256, 0, stream>>>(cnt, off, bsum, nbins);
    k_scan_add<<<(nbins + 255)/256, 256, 0, stream>>>(off, cur, bsum, cnt, nbins);
    k_scatter_key<<<(E + 255)/256, 256, 0, stream>>>(dst, ea, src, cur, psrc, E);

    k_gemm_layer<<<dim3((N + 63)/64, 9), 256, 0, stream>>>(
        xbf, wt, bl, br, skip_b, xlb, xrb, out1, li, N, nt);
    k_dst_agg<<<nt, 256, 0, stream>>>(
        off, psrc, xlb, xrb, att + li*512,
        conv_b + li*512, bn_g + li*512, bn_b + li*512, bn_m + li*512, bn_v + li*512,
        out1, outBf, outF32, N, nt);
  };

  float* outX = (float*)d_out;
  float* outP = (float*)d_out + (size_t)N2*128;

  run_layer(0, N0, N1, src0, dst0, ea0, E0, xbf, nullptr);
  run_layer(1, N1, N2, src1, dst1, ea1, E1, xbf, outX);

  k_gemm_proj<<<(N2 + 63)/64, 256, 0, stream>>>(
      xbf, N2, wt + 18*16384, proj_b, pbn_g, pbn_b, pbn_m, pbn_v, prelu_a, outP);
}